// Round 5
// baseline (352.023 us; speedup 1.0000x reference)
//
#include <hip/hip_runtime.h>
#include <hip/hip_bf16.h>
#include <math.h>

#define B_SZ    32
#define LSEQ    1024
#define DIN     128
#define HDIM    256
#define NLAYERS 4
#define NSTATE  32
#define DOUT    10
#define M_ROWS  (B_SZ*LSEQ)   // 32768
#define CH      64            // scan chunk length
#define NCH     (LSEQ/CH)     // 16 chunks
#define NBC     (B_SZ*NCH)    // 512 chunk-columns

typedef __hip_bfloat16 bf16;
typedef __attribute__((ext_vector_type(8))) short bf16x8;
typedef __attribute__((ext_vector_type(4))) float f32x4;

__device__ __forceinline__ unsigned short f2bu(float x) {
    bf16 b = __float2bfloat16(x);
    return *(unsigned short*)&b;
}
__device__ __forceinline__ float bu2f(unsigned short u) {
    bf16 b = *(bf16*)&u;
    return __bfloat162float(b);
}

// inline S4D discretization: returns (dtAre, dtAim, Wre, Wim)
__device__ __forceinline__ float4 s4param(const float* __restrict__ log_dt,
                                          const float* __restrict__ A_re_log,
                                          const float* __restrict__ A_im,
                                          const float* __restrict__ B_re,
                                          const float* __restrict__ B_im,
                                          const float* __restrict__ C_re,
                                          const float* __restrict__ C_im,
                                          int layer, int h, int n) {
    int hn = layer * HDIM + h;
    int idx = hn * NSTATE + n;
    float dt   = expf(log_dt[hn]);
    float Are  = -expf(A_re_log[idx]);
    float Aim  = A_im[idx];
    float dtAre = dt * Are, dtAim = dt * Aim;
    float ea   = expf(dtAre);
    float dAre = ea * cosf(dtAim), dAim = ea * sinf(dtAim);
    float nre = dAre - 1.0f, nim = dAim;
    float inv = 1.0f / (Are * Are + Aim * Aim);
    float tre = (nre * Are + nim * Aim) * inv;
    float tim = (nim * Are - nre * Aim) * inv;
    float Brv = B_re[idx], Biv = B_im[idx];
    float dBre = Brv * tre - Biv * tim;
    float dBim = Brv * tim + Biv * tre;
    float Crv = C_re[idx], Civ = C_im[idx];
    float Wre = Crv * dBre - Civ * dBim;
    float Wim = Crv * dBim + Civ * dBre;
    return make_float4(dtAre, dtAim, Wre, Wim);
}

// ---------------- ONE setup kernel: V/M, Td, PA64, weight transposes ----------------
// r3: Vg and Wt stored FRAGMENT-MAJOR so consumer wave-loads are base+lane*16B coalesced.
#define VMB_ (NLAYERS*HDIM*64*32/256)    // 8192
#define TDB_ ((NLAYERS*HDIM*66+255)/256) // 264
#define PAB_ (NLAYERS*NSTATE*HDIM/256)   // 128
#define WCB_ (NLAYERS*512*256/256)       // 2048
__global__ void k_setup(const float* __restrict__ log_dt, const float* __restrict__ A_re_log,
                        const float* __restrict__ A_im, const float* __restrict__ B_re,
                        const float* __restrict__ B_im, const float* __restrict__ C_re,
                        const float* __restrict__ C_im, const float* __restrict__ out_w,
                        const float* __restrict__ enc_w, float* __restrict__ Td,
                        bf16* __restrict__ Vg, bf16* __restrict__ Mg,
                        float2* __restrict__ PA64, bf16* __restrict__ Wt,
                        bf16* __restrict__ Wet) {
    const float inv2pi = 0.15915494309189535f;
    const float twopi  = 6.283185307179586f;
    int bx = blockIdx.x;
    if (bx < VMB_) {                                 // V/M pair-elements
        int gid = bx * 256 + threadIdx.x;
        int jp = (gid & 31) * 2;
        int row = gid >> 5;                          // ((layer*256+h)*64)+comp
        int comp = row & 63, h = (row >> 6) & 255, layer = row >> 14;
        int n = comp >> 1, isIm = comp & 1;
        float4 q = s4param(log_dt, A_re_log, A_im, B_re, B_im, C_re, C_im, layer, h, n);
        unsigned int vpk = 0, mpk = 0;
#pragma unroll
        for (int e = 0; e < 2; ++e) {
            int j = jp + e;
            float dv = (float)(63 - j);
            float magv = __expf(dv * q.x);
            float pr = dv * q.y * inv2pi;
            float th = (pr - floorf(pr)) * twopi;
            float c = __cosf(th), s = __sinf(th);
            float vre = magv * (q.z * c - q.w * s);
            float vim = magv * (q.z * s + q.w * c);
            vpk |= (unsigned int)f2bu(isIm ? vim : vre) << (16 * e);
            float dm = (float)(j + 1);
            float magm = __expf(dm * q.x);
            float pr2 = dm * q.y * inv2pi;
            float th2 = (pr2 - floorf(pr2)) * twopi;
            float mv = isIm ? (-2.f * magm * __sinf(th2)) : (2.f * magm * __cosf(th2));
            mpk |= (unsigned int)f2bu(mv) << (16 * e);
        }
        // V fragment-major within (layer,h) 64x64 block
        {
            int mtv = comp >> 4, frv = comp & 15;
            int ksv = jp >> 5, qdv = (jp >> 3) & 3, ev = jp & 7;
            size_t voff = (size_t)(layer * 256 + h) * 4096
                        + ((size_t)((mtv * 2 + ksv) * 64) + qdv * 16 + frv) * 8 + ev;
            ((unsigned int*)Vg)[voff >> 1] = vpk;    // jp even -> voff even
        }
        ((unsigned int*)Mg)[(size_t)row * 32 + (jp >> 1)] = mpk;   // M row-major (LDS-staged)
    } else if (bx < VMB_ + TDB_) {                   // Td
        int gid = (bx - VMB_) * 256 + threadIdx.x;
        int d = gid % 66;
        int lh = gid / 66;
        if (lh < NLAYERS * HDIM && d < 65) {
            int layer = lh >> 8, h = lh & 255;
            float fd = (float)d;
            float acc = 0.f;
            for (int n = 0; n < NSTATE; ++n) {
                float4 q = s4param(log_dt, A_re_log, A_im, B_re, B_im, C_re, C_im, layer, h, n);
                float mag = __expf(fd * q.x);
                float pr = fd * q.y * inv2pi;
                float th = (pr - floorf(pr)) * twopi;
                acc += mag * (q.z * __cosf(th) - q.w * __sinf(th));
            }
            Td[(size_t)lh * 66 + d] = 2.f * acc;
        }
    } else if (bx < VMB_ + TDB_ + PAB_) {            // PA64 = dA^64 per (layer,n,h)
        int idx = (bx - VMB_ - TDB_) * 256 + threadIdx.x;
        int h = idx & 255, n = (idx >> 8) & 31, layer = idx >> 13;
        float4 q = s4param(log_dt, A_re_log, A_im, B_re, B_im, C_re, C_im, layer, h, n);
        float e64 = expf(64.0f * q.x);
        float ph  = 64.0f * q.y;
        PA64[idx] = make_float2(e64 * cosf(ph), e64 * sinf(ph));
    } else if (bx < VMB_ + TDB_ + PAB_ + WCB_) {     // Wt fragment-major
        int idx = (bx - VMB_ - TDB_ - PAB_) * 256 + threadIdx.x;
        int k = idx & 255;
        int n = (idx >> 8) & 511;
        int layer = idx >> 17;
        // [nb=n>>4][ks=k>>5][quad=(k>>3)&3][fr=n&15][e=k&7]
        size_t off = (size_t)layer * (512 * 256)
                   + ((size_t)((n >> 4) * 8 + (k >> 5)) * 64 + (((k >> 3) & 3) * 16 + (n & 15))) * 8
                   + (k & 7);
        Wt[off] = __float2bfloat16(out_w[((size_t)(layer * 256 + k)) * 512 + n]);
    } else {                                         // Wet transpose
        int idx = (bx - VMB_ - TDB_ - PAB_ - WCB_) * 256 + threadIdx.x;
        int k = idx & 127, n = idx >> 7;
        Wet[idx] = __float2bfloat16(enc_w[(size_t)k * HDIM + n]);
    }
}

// ---------------- encoder GEMM (bf16 MFMA): H(bf16) = X@We + b, + transposed Ut ----------------
__global__ __launch_bounds__(256) void k_enc2(const float* __restrict__ X, const bf16* __restrict__ Wet,
                                              const float* __restrict__ bias, bf16* __restrict__ H,
                                              bf16* __restrict__ Ut) {
    __shared__ bf16 A_s[128 * 136];
    __shared__ bf16 B_s[64 * 136];
    int tid = threadIdx.x;
    int lane = tid & 63, wv = tid >> 6, quad = lane >> 4, fr = lane & 15;
    int m0 = blockIdx.x * 128, n0 = blockIdx.y * 64;
#pragma unroll
    for (int i = 0; i < 16; ++i) {               // stage X fp32 -> bf16 [m][k]
        int q = tid + i * 256, row = q >> 5, seg = q & 31;
        float4 v = *(const float4*)&X[(size_t)(m0 + row) * DIN + seg * 4];
        bf16* dst = &A_s[row * 136 + seg * 4];
        dst[0] = __float2bfloat16(v.x); dst[1] = __float2bfloat16(v.y);
        dst[2] = __float2bfloat16(v.z); dst[3] = __float2bfloat16(v.w);
    }
#pragma unroll
    for (int i = 0; i < 4; ++i) {                // stage Wet [n][k]
        int q = tid + i * 256, row = q >> 4, seg = q & 15;
        *(uint4*)&B_s[row * 136 + seg * 8] = *(const uint4*)&Wet[(size_t)(n0 + row) * DIN + seg * 8];
    }
    __syncthreads();
    f32x4 acc[2][4];
#pragma unroll
    for (int mt = 0; mt < 2; ++mt)
#pragma unroll
        for (int nt = 0; nt < 4; ++nt) acc[mt][nt] = (f32x4){0.f, 0.f, 0.f, 0.f};
#pragma unroll
    for (int ks = 0; ks < 4; ++ks) {
        bf16x8 a[2], b[4];
#pragma unroll
        for (int mt = 0; mt < 2; ++mt)
            a[mt] = *(const bf16x8*)&A_s[(wv * 32 + mt * 16 + fr) * 136 + ks * 32 + quad * 8];
#pragma unroll
        for (int nt = 0; nt < 4; ++nt)
            b[nt] = *(const bf16x8*)&B_s[(nt * 16 + fr) * 136 + ks * 32 + quad * 8];
#pragma unroll
        for (int mt = 0; mt < 2; ++mt)
#pragma unroll
            for (int nt = 0; nt < 4; ++nt)
                acc[mt][nt] = __builtin_amdgcn_mfma_f32_16x16x32_bf16(a[mt], b[nt], acc[mt][nt], 0, 0, 0);
    }
    __syncthreads();                             // B_s reuse as transpose bounce
#pragma unroll
    for (int mt = 0; mt < 2; ++mt)
#pragma unroll
        for (int nt = 0; nt < 4; ++nt) {
            int n = n0 + nt * 16 + fr;
            float bv = bias[n];
#pragma unroll
            for (int r = 0; r < 4; ++r) {
                int m = m0 + wv * 32 + mt * 16 + quad * 4 + r;
                float hv = acc[mt][nt][r] + bv;
                bf16 hb = __float2bfloat16(hv);
                H[(size_t)m * HDIM + n] = hb;
                B_s[(nt * 16 + fr) * 136 + (wv * 32 + mt * 16 + quad * 4 + r)] = hb;
            }
        }
    __syncthreads();
#pragma unroll
    for (int i = 0; i < 4; ++i) {                // coalesced Ut store [h][m]
        int q = tid + i * 256, row = q >> 4, seg = q & 15;
        *(uint4*)&Ut[(size_t)(n0 + row) * M_ROWS + m0 + seg * 8] = *(uint4*)&B_s[row * 136 + seg * 8];
    }
}

// ---------------- fused conv: u from global (L2-hot), LDS 35.8 KB -> 4 blocks/CU ----------------
__global__ __launch_bounds__(256) void k_conv(const bf16* __restrict__ Ut,
                                              const bf16* __restrict__ Vg,
                                              const bf16* __restrict__ Mg,
                                              const float* __restrict__ Tdl,
                                              const float2* __restrict__ PA,
                                              const float* __restrict__ Dw,
                                              bf16* __restrict__ Yt) {
    __shared__ bf16 A_s[64 * 136];               // [l][k2], k2<64: T, k2>=64: M
    __shared__ bf16 Eo_s[128 * 72];              // [bc][comp]: E, then carries, then o_s
    int h = blockIdx.x, bc0 = blockIdx.y * 128;
    int tid = threadIdx.x;
    int lane = tid & 63, wv = tid >> 6, quad = lane >> 4, fr = lane & 15;
    const float* Tdh = Tdl + (size_t)h * 66;
    const bf16* Uh = Ut + (size_t)h * M_ROWS + (size_t)bc0 * 64;
    // hoist ALL E-phase global fragments first (12 independent loads, batched issue)
    bf16x8 va[2][4], ub[2][2];
#pragma unroll
    for (int ks = 0; ks < 2; ++ks) {
#pragma unroll
        for (int mt = 0; mt < 4; ++mt)           // fragment-major Vg: coalesced
            va[ks][mt] = *(const bf16x8*)&Vg[(size_t)h * 4096 + ((size_t)((mt * 2 + ks) * 64) + lane) * 8];
#pragma unroll
        for (int nf = 0; nf < 2; ++nf)
            ub[ks][nf] = *(const bf16x8*)&Uh[(size_t)(wv * 32 + nf * 16 + fr) * 64 + ks * 32 + quad * 8];
    }
#pragma unroll
    for (int i = 0; i < 2; ++i) {                // stage M transposed into A_s cols 64..127
        int q = tid + i * 256, comp = q >> 3, seg = q & 7;
        uint4 v = *(const uint4*)&Mg[((size_t)h * 64 + comp) * 64 + seg * 8];
        const bf16* pv = (const bf16*)&v;
#pragma unroll
        for (int e = 0; e < 8; ++e) A_s[(seg * 8 + e) * 136 + 64 + comp] = pv[e];
    }
#pragma unroll
    for (int i = 0; i < 16; ++i) {               // Toeplitz T fill (Td direct from L2)
        int q = tid + i * 256, l = q >> 6, j = q & 63, d = l - j;
        A_s[l * 136 + j] = __float2bfloat16(d >= 0 ? Tdh[d] : 0.f);
    }
    f32x4 eacc[4][2];
#pragma unroll
    for (int mt = 0; mt < 4; ++mt)
#pragma unroll
        for (int nf = 0; nf < 2; ++nf) eacc[mt][nf] = (f32x4){0.f, 0.f, 0.f, 0.f};
#pragma unroll
    for (int ks = 0; ks < 2; ++ks)
#pragma unroll
        for (int mt = 0; mt < 4; ++mt)
#pragma unroll
            for (int nf = 0; nf < 2; ++nf)
                eacc[mt][nf] = __builtin_amdgcn_mfma_f32_16x16x32_bf16(va[ks][mt], ub[ks][nf], eacc[mt][nf], 0, 0, 0);
#pragma unroll
    for (int mt = 0; mt < 4; ++mt)               // E -> Eo_s [bc][comp], packed pairs
#pragma unroll
        for (int nf = 0; nf < 2; ++nf) {
            int bc = wv * 32 + nf * 16 + fr;
#pragma unroll
            for (int r = 0; r < 4; r += 2) {
                int comp = mt * 16 + quad * 4 + r;
                *(unsigned int*)&Eo_s[bc * 72 + comp] =
                    (unsigned int)f2bu(eacc[mt][nf][r]) | ((unsigned int)f2bu(eacc[mt][nf][r + 1]) << 16);
            }
        }
    __syncthreads();                             // Eo + A_s ready
    {                                            // in-place carry scan: thread = (b_local, n)
        int bl = tid >> 5, n = tid & 31;
        float2 a = PA[n * HDIM + h];
        float cr = 0.f, ci = 0.f;
#pragma unroll
        for (int c = 0; c < NCH; ++c) {
            int bc = bl * NCH + c;
            unsigned int* slot = (unsigned int*)&Eo_s[bc * 72 + 2 * n];
            unsigned int ev = *slot;
            *slot = (unsigned int)f2bu(cr) | ((unsigned int)f2bu(ci) << 16);
            float er = bu2f((unsigned short)(ev & 0xffff));
            float ei = bu2f((unsigned short)(ev >> 16));
            float nr = fmaf(a.x, cr, fmaf(-a.y, ci, er));
            ci = fmaf(a.x, ci, fmaf(a.y, cr, ei));
            cr = nr;
        }
    }
    __syncthreads();                             // carries in Eo_s
    f32x4 acc[4][2];
#pragma unroll
    for (int mt = 0; mt < 4; ++mt)
#pragma unroll
        for (int nf = 0; nf < 2; ++nf) acc[mt][nf] = (f32x4){0.f, 0.f, 0.f, 0.f};
#pragma unroll
    for (int ks = 0; ks < 4; ++ks) {
        bf16x8 a[4], b[2];
#pragma unroll
        for (int mt = 0; mt < 4; ++mt)
            a[mt] = *(const bf16x8*)&A_s[(mt * 16 + fr) * 136 + ks * 32 + quad * 8];
#pragma unroll
        for (int nf = 0; nf < 2; ++nf) {
            int row = wv * 32 + nf * 16 + fr;
            b[nf] = (ks < 2) ? ub[ks][nf]        // reuse regs: same addresses as E-phase loads
                             : *(const bf16x8*)&Eo_s[row * 72 + (ks - 2) * 32 + quad * 8];
        }
#pragma unroll
        for (int mt = 0; mt < 4; ++mt)
#pragma unroll
            for (int nf = 0; nf < 2; ++nf)
                acc[mt][nf] = __builtin_amdgcn_mfma_f32_16x16x32_bf16(a[mt], b[nf], acc[mt][nf], 0, 0, 0);
    }
    float Dv = Dw[h];
    // epilogue: u via uint2 gathers (L2-hot); writes only this wave's own Eo_s rows
#pragma unroll
    for (int mt = 0; mt < 4; ++mt)
#pragma unroll
        for (int nf = 0; nf < 2; ++nf) {
            int bcl = wv * 32 + nf * 16 + fr;
            uint2 uv = *(const uint2*)&Uh[(size_t)bcl * 64 + mt * 16 + quad * 4];
            const bf16* up = (const bf16*)&uv;
#pragma unroll
            for (int r = 0; r < 4; ++r) {
                int l = mt * 16 + quad * 4 + r;
                float u = __bfloat162float(up[r]);
                float v = fmaf(Dv, u, acc[mt][nf][r]);
                float z2 = 1.5957691216057308f * (v + 0.044715f * v * v * v);
                Eo_s[bcl * 72 + l] = __float2bfloat16(v / (1.f + __expf(-z2)));
            }
        }
    __syncthreads();
#pragma unroll
    for (int i = 0; i < 4; ++i) {                // coalesced Yt store
        int q = tid + i * 256, row = q >> 3, c8 = q & 7;
        *(uint4*)&Yt[(size_t)h * M_ROWS + (size_t)(bc0 + row) * 64 + c8 * 8] =
            *(uint4*)&Eo_s[row * 72 + c8 * 8];
    }
}

// ---------------- FUSED output GEMM + GLU + residual + LayerNorm (+ decoder on last layer) ----
// r5: 2-tile pipelined block (grid 512, m=64/block). A-tile(t+1) Yt loads + Hb(t+1) residual
// loads issued during tile t's GEMM -> L3 latency (cross-XCD Yt) hidden under ~3000cy compute.
// Hb(0) prefetched at kernel start. Double-buffered A_s; A(1) packed during GLU(0).
__global__ __launch_bounds__(256) void k_gluln(const bf16* __restrict__ Yt,
                                               const bf16* __restrict__ Wt,
                                               const float* __restrict__ wb,
                                               bf16* __restrict__ Hb,
                                               const float* __restrict__ w,
                                               const float* __restrict__ bbias,
                                               bf16* __restrict__ Ut,
                                               const float* __restrict__ dw,
                                               const float* __restrict__ db,
                                               float* __restrict__ outp, int mode) {
    __shared__ __align__(16) bf16 A_s[2][32 * 264];  // per-tile A [m][k]; then g [m][n]; mode1: dw
    __shared__ float red[2][8][32];
    __shared__ float stat[2][32];
    __shared__ float w_s[256], b_s[256];
    __shared__ float db_s[16];
    int tid = threadIdx.x;
    int lane = tid & 63, wv = tid >> 6;
    int quad = lane >> 4, fr = lane & 15;
    int mg = tid & 7, hg = tid >> 3;             // A-stage coords
    int rr = tid & 31, qd = tid >> 5;            // LN coords
    int mbase = blockIdx.x * 64;
    w_s[tid] = w[tid]; b_s[tid] = bbias[tid];
    if (mode == 1 && tid < DOUT) db_s[tid] = db[tid];
    float bias1[4], bias2[4];
#pragma unroll
    for (int nt = 0; nt < 4; ++nt) {             // GLU biases -> regs (L2-hot)
        bias1[nt] = wb[wv * 64 + nt * 16 + fr];
        bias2[nt] = wb[HDIM + wv * 64 + nt * 16 + fr];
    }
    uint2 rowv[8];
    uint4 hbv0[4], hbv1[4];
    f32x4 acc1[2][4], acc2[2][4];
    float rv[32];
    float sum, sq;

#define PACK_A(BUF) do { \
    _Pragma("unroll") \
    for (int j = 0; j < 4; ++j) { \
        unsigned int pk[4]; \
        _Pragma("unroll") \
        for (int k2 = 0; k2 < 4; ++k2) { \
            unsigned int lo = ((const unsigned short*)&rowv[2 * k2])[j]; \
            unsigned int hi = ((const unsigned short*)&rowv[2 * k2 + 1])[j]; \
            pk[k2] = lo | (hi << 16); \
        } \
        *(uint4*)&A_s[BUF][(mg * 4 + j) * 264 + hg * 8] = *(uint4*)pk; \
    } } while (0)

#define LOAD_B(d1, d2, KS) do { \
    _Pragma("unroll") \
    for (int nt = 0; nt < 4; ++nt) { \
        d1[nt] = *(const bf16x8*)&Wt[((size_t)((wv * 4 + nt) * 8 + (KS)) * 64 + lane) * 8]; \
        d2[nt] = *(const bf16x8*)&Wt[((size_t)((16 + wv * 4 + nt) * 8 + (KS)) * 64 + lane) * 8]; \
    } } while (0)

#define DO_MFMA(bb1, bb2, KS, BUF) do { \
    bf16x8 afr[2]; \
    _Pragma("unroll") \
    for (int mt = 0; mt < 2; ++mt) \
        afr[mt] = *(const bf16x8*)&A_s[BUF][(mt * 16 + fr) * 264 + (KS) * 32 + quad * 8]; \
    _Pragma("unroll") \
    for (int mt = 0; mt < 2; ++mt) \
        _Pragma("unroll") \
        for (int nt = 0; nt < 4; ++nt) { \
            acc1[mt][nt] = __builtin_amdgcn_mfma_f32_16x16x32_bf16(afr[mt], bb1[nt], acc1[mt][nt], 0, 0, 0); \
            acc2[mt][nt] = __builtin_amdgcn_mfma_f32_16x16x32_bf16(afr[mt], bb2[nt], acc2[mt][nt], 0, 0, 0); \
        } } while (0)

#define RUN_GEMM(BUF) do { \
    _Pragma("unroll") \
    for (int mt = 0; mt < 2; ++mt) \
        _Pragma("unroll") \
        for (int nt = 0; nt < 4; ++nt) { \
            acc1[mt][nt] = (f32x4){0.f, 0.f, 0.f, 0.f}; \
            acc2[mt][nt] = (f32x4){0.f, 0.f, 0.f, 0.f}; \
        } \
    bf16x8 p1[4], p2[4], q1[4], q2[4]; \
    LOAD_B(p1, p2, 0); \
    _Pragma("unroll") \
    for (int kp = 0; kp < 4; ++kp) { \
        LOAD_B(q1, q2, 2 * kp + 1); \
        DO_MFMA(p1, p2, 2 * kp, BUF); \
        if (kp < 3) LOAD_B(p1, p2, 2 * kp + 2); \
        DO_MFMA(q1, q2, 2 * kp + 1, BUF); \
    } } while (0)

#define GLU_WRITE(BUF) do { \
    _Pragma("unroll") \
    for (int mt = 0; mt < 2; ++mt) \
        _Pragma("unroll") \
        for (int nt = 0; nt < 4; ++nt) { \
            int n = wv * 64 + nt * 16 + fr; \
            _Pragma("unroll") \
            for (int r = 0; r < 4; ++r) { \
                int m = mt * 16 + quad * 4 + r; \
                float z1 = acc1[mt][nt][r] + bias1[nt]; \
                float z2 = acc2[mt][nt][r] + bias2[nt]; \
                A_s[BUF][m * 264 + n] = __float2bfloat16(z1 / (1.0f + __expf(-z2))); \
            } \
        } } while (0)

#define LN_PHASE(BUF, HBV, M0) do { \
    sum = 0.f; sq = 0.f; \
    _Pragma("unroll") \
    for (int i4 = 0; i4 < 4; ++i4) { \
        uint4 gv = *(uint4*)&A_s[BUF][rr * 264 + qd * 32 + i4 * 8]; \
        const bf16* gp = (const bf16*)&gv; \
        const bf16* hp = (const bf16*)&HBV[i4]; \
        _Pragma("unroll") \
        for (int e = 0; e < 8; ++e) { \
            float v = __bfloat162float(gp[e]) + __bfloat162float(hp[e]); \
            rv[i4 * 8 + e] = v; sum += v; sq += v * v; \
        } \
    } \
    red[0][qd][rr] = sum; red[1][qd][rr] = sq; \
    __syncthreads(); \
    if (tid < 32) { \
        float s = 0.f, s2 = 0.f; \
        _Pragma("unroll") \
        for (int q = 0; q < 8; ++q) { s += red[0][q][tid]; s2 += red[1][q][tid]; } \
        float mean_ = s * (1.f / HDIM); \
        float var_ = s2 * (1.f / HDIM) - mean_ * mean_; \
        stat[0][tid] = mean_; stat[1][tid] = rsqrtf(var_ + 1e-5f); \
    } \
    __syncthreads(); \
    { \
        float mean = stat[0][rr], rstd = stat[1][rr]; \
        _Pragma("unroll") \
        for (int j = 0; j < 32; ++j) \
            rv[j] = (rv[j] - mean) * rstd * w_s[qd * 32 + j] + b_s[qd * 32 + j]; \
    } \
    if (mode == 0) { \
        bf16* Hw = Hb + (size_t)((M0) + rr) * HDIM + qd * 32; \
        _Pragma("unroll") \
        for (int j = 0; j < 32; j += 8) { \
            unsigned int pk[4]; \
            _Pragma("unroll") \
            for (int e = 0; e < 4; ++e) \
                pk[e] = (unsigned int)f2bu(rv[j + 2 * e]) | ((unsigned int)f2bu(rv[j + 2 * e + 1]) << 16); \
            *(uint4*)&Hw[j] = *(uint4*)pk; \
        } \
        bf16* Up = Ut + (size_t)(qd * 32) * M_ROWS + (M0) + rr; \
        _Pragma("unroll") \
        for (int j = 0; j < 32; ++j) \
            Up[(size_t)j * M_ROWS] = __float2bfloat16(rv[j]); \
    } else { \
        __syncthreads(); \
        float* dwf = (float*)A_s[BUF]; \
        for (int e = tid; e < HDIM * DOUT; e += 256) dwf[e] = dw[e]; \
        __syncthreads(); \
        float part[DOUT]; \
        _Pragma("unroll") \
        for (int o = 0; o < DOUT; ++o) part[o] = 0.f; \
        _Pragma("unroll") \
        for (int j = 0; j < 32; ++j) { \
            float tv = rv[j]; \
            const float* dr = &dwf[(qd * 32 + j) * DOUT]; \
            _Pragma("unroll") \
            for (int o = 0; o < DOUT; ++o) part[o] = fmaf(tv, dr[o], part[o]); \
        } \
        _Pragma("unroll") \
        for (int oc = 0; oc < 5; ++oc) { \
            red[0][qd][rr] = part[2 * oc]; \
            red[1][qd][rr] = part[2 * oc + 1]; \
            __syncthreads(); \
            if (tid < 64) { \
                int rl = tid & 31, ph = tid >> 5; \
                float s = 0.f; \
                _Pragma("unroll") \
                for (int q = 0; q < 8; ++q) s += red[ph][q][rl]; \
                int o = 2 * oc + ph; \
                outp[(size_t)((M0) + rl) * DOUT + o] = s + db_s[o]; \
            } \
            __syncthreads(); \
        } \
    } } while (0)

    // ---- prologue: prefetch tile 0 (A + residual) ----
#pragma unroll
    for (int e = 0; e < 8; ++e)
        rowv[e] = *(const uint2*)&Yt[(size_t)(hg * 8 + e) * M_ROWS + mbase + mg * 4];
#pragma unroll
    for (int i = 0; i < 4; ++i)
        hbv0[i] = *(const uint4*)&Hb[(size_t)(mbase + rr) * HDIM + qd * 32 + i * 8];
    PACK_A(0);
    __syncthreads();                             // A_s[0] ready
    // ---- prefetch tile 1 (hidden under GEMM(0)+GLU(0)) ----
#pragma unroll
    for (int e = 0; e < 8; ++e)
        rowv[e] = *(const uint2*)&Yt[(size_t)(hg * 8 + e) * M_ROWS + mbase + 32 + mg * 4];
#pragma unroll
    for (int i = 0; i < 4; ++i)
        hbv1[i] = *(const uint4*)&Hb[(size_t)(mbase + 32 + rr) * HDIM + qd * 32 + i * 8];
    // ---- tile 0 ----
    RUN_GEMM(0);
    __syncthreads();                             // A_s[0] reads done
    GLU_WRITE(0);
    PACK_A(1);                                   // stage next A into idle buffer
    __syncthreads();                             // g(0) + A_s[1] ready
    LN_PHASE(0, hbv0, mbase);
    // ---- tile 1 ----
    RUN_GEMM(1);
    __syncthreads();                             // A_s[1] reads done (also fences red/stat reuse)
    GLU_WRITE(1);
    __syncthreads();                             // g(1) ready
    LN_PHASE(1, hbv1, mbase + 32);

#undef PACK_A
#undef LOAD_B
#undef DO_MFMA
#undef RUN_GEMM
#undef GLU_WRITE
#undef LN_PHASE
}

extern "C" void kernel_launch(void* const* d_in, const int* in_sizes, int n_in,
                              void* d_out, int out_size, void* d_ws, size_t ws_size,
                              hipStream_t stream) {
    const float* x        = (const float*)d_in[0];
    const float* enc_w    = (const float*)d_in[1];
    const float* enc_b    = (const float*)d_in[2];
    const float* log_dt   = (const float*)d_in[3];
    const float* A_re_log = (const float*)d_in[4];
    const float* A_im     = (const float*)d_in[5];
    const float* B_re     = (const float*)d_in[6];
    const float* B_im     = (const float*)d_in[7];
    const float* C_re     = (const float*)d_in[8];
    const float* C_im     = (const float*)d_in[9];
    const float* Dp       = (const float*)d_in[10];
    const float* ln_w     = (const float*)d_in[11];
    const float* ln_b     = (const float*)d_in[12];
    const float* out_w    = (const float*)d_in[13];
    const float* out_b    = (const float*)d_in[14];
    const float* dec_w    = (const float*)d_in[15];
    const float* dec_b    = (const float*)d_in[16];
    float* outp = (float*)d_out;

    float* w = (float*)d_ws;
    const size_t PWE = (size_t)NLAYERS * NSTATE * HDIM;   // 32768
    const size_t MH  = (size_t)M_ROWS * HDIM;             // 8388608
    const size_t VME = (size_t)NLAYERS * HDIM * 64 * 64;  // 4M elems/matrix
    float2* PA64 = (float2*)(w + 4 * PWE);                // 256 KB
    float*  Td   = w + 6 * PWE;                           // 270 KB
    bf16*   Hbuf = (bf16*)(Td + (size_t)NLAYERS * HDIM * 66);  // 16.7 MB bf16
    bf16*   Ut   = Hbuf + MH;                             // 16.7 MB
    bf16*   Yt   = Ut + MH;                               // 16.7 MB
    bf16*   Wt   = Yt + MH;                               // 1 MB (G buffer eliminated)
    bf16*   Wet  = Wt + (size_t)NLAYERS * 512 * HDIM;     // 64 KB
    bf16*   Vg   = Wet + (size_t)HDIM * DIN;              // 8 MB (all layers)
    bf16*   Mg   = Vg + VME;                              // 8 MB (all layers)

    {
        int total = VMB_ + TDB_ + PAB_ + WCB_ + HDIM * DIN / 256;
        k_setup<<<total, 256, 0, stream>>>(log_dt, A_re_log, A_im, B_re, B_im, C_re, C_im,
                                           out_w, enc_w, Td, Vg, Mg, PA64, Wt, Wet);
    }

    dim3 ge(M_ROWS / 128, HDIM / 64);
    k_enc2<<<ge, 256, 0, stream>>>(x, Wet, enc_b, Hbuf, Ut);

    dim3 gconv(HDIM, NBC / 128);
    for (int layer = 0; layer < NLAYERS; ++layer) {
        const float2* pal = PA64 + (size_t)layer * NSTATE * HDIM;
        const float*  tdl = Td + (size_t)layer * HDIM * 66;
        const bf16*   vgl = Vg + (size_t)layer * HDIM * 64 * 64;
        const bf16*   mgl = Mg + (size_t)layer * HDIM * 64 * 64;
        k_conv<<<gconv, 256, 0, stream>>>(Ut, vgl, mgl, tdl, pal, Dp + layer * HDIM, Yt);
        k_gluln<<<M_ROWS / 64, 256, 0, stream>>>(Yt, Wt + (size_t)layer * 512 * HDIM,
                                                 out_b + layer * 2 * HDIM, Hbuf,
                                                 ln_w + layer * HDIM, ln_b + layer * HDIM,
                                                 Ut, dec_w, dec_b, outp,
                                                 layer == NLAYERS - 1 ? 1 : 0);
    }
}

// Round 6
// 320.822 us; speedup vs baseline: 1.0973x; 1.0973x over previous
//
#include <hip/hip_runtime.h>
#include <hip/hip_bf16.h>
#include <math.h>

#define B_SZ    32
#define LSEQ    1024
#define DIN     128
#define HDIM    256
#define NLAYERS 4
#define NSTATE  32
#define DOUT    10
#define M_ROWS  (B_SZ*LSEQ)   // 32768
#define CH      64            // scan chunk length
#define NCH     (LSEQ/CH)     // 16 chunks
#define NBC     (B_SZ*NCH)    // 512 chunk-columns

typedef __hip_bfloat16 bf16;
typedef __attribute__((ext_vector_type(8))) short bf16x8;
typedef __attribute__((ext_vector_type(4))) float f32x4;

__device__ __forceinline__ unsigned short f2bu(float x) {
    bf16 b = __float2bfloat16(x);
    return *(unsigned short*)&b;
}
__device__ __forceinline__ float bu2f(unsigned short u) {
    bf16 b = *(bf16*)&u;
    return __bfloat162float(b);
}

// inline S4D discretization: returns (dtAre, dtAim, Wre, Wim)
__device__ __forceinline__ float4 s4param(const float* __restrict__ log_dt,
                                          const float* __restrict__ A_re_log,
                                          const float* __restrict__ A_im,
                                          const float* __restrict__ B_re,
                                          const float* __restrict__ B_im,
                                          const float* __restrict__ C_re,
                                          const float* __restrict__ C_im,
                                          int layer, int h, int n) {
    int hn = layer * HDIM + h;
    int idx = hn * NSTATE + n;
    float dt   = expf(log_dt[hn]);
    float Are  = -expf(A_re_log[idx]);
    float Aim  = A_im[idx];
    float dtAre = dt * Are, dtAim = dt * Aim;
    float ea   = expf(dtAre);
    float dAre = ea * cosf(dtAim), dAim = ea * sinf(dtAim);
    float nre = dAre - 1.0f, nim = dAim;
    float inv = 1.0f / (Are * Are + Aim * Aim);
    float tre = (nre * Are + nim * Aim) * inv;
    float tim = (nim * Are - nre * Aim) * inv;
    float Brv = B_re[idx], Biv = B_im[idx];
    float dBre = Brv * tre - Biv * tim;
    float dBim = Brv * tim + Biv * tre;
    float Crv = C_re[idx], Civ = C_im[idx];
    float Wre = Crv * dBre - Civ * dBim;
    float Wim = Crv * dBim + Civ * dBre;
    return make_float4(dtAre, dtAim, Wre, Wim);
}

// ---------------- ONE setup kernel: V/M, Td, PA64, weight transposes ----------------
// r3: Vg and Wt stored FRAGMENT-MAJOR so consumer wave-loads are base+lane*16B coalesced.
#define VMB_ (NLAYERS*HDIM*64*32/256)    // 8192
#define TDB_ ((NLAYERS*HDIM*66+255)/256) // 264
#define PAB_ (NLAYERS*NSTATE*HDIM/256)   // 128
#define WCB_ (NLAYERS*512*256/256)       // 2048
__global__ void k_setup(const float* __restrict__ log_dt, const float* __restrict__ A_re_log,
                        const float* __restrict__ A_im, const float* __restrict__ B_re,
                        const float* __restrict__ B_im, const float* __restrict__ C_re,
                        const float* __restrict__ C_im, const float* __restrict__ out_w,
                        const float* __restrict__ enc_w, float* __restrict__ Td,
                        bf16* __restrict__ Vg, bf16* __restrict__ Mg,
                        float2* __restrict__ PA64, bf16* __restrict__ Wt,
                        bf16* __restrict__ Wet) {
    const float inv2pi = 0.15915494309189535f;
    const float twopi  = 6.283185307179586f;
    int bx = blockIdx.x;
    if (bx < VMB_) {                                 // V/M pair-elements
        int gid = bx * 256 + threadIdx.x;
        int jp = (gid & 31) * 2;
        int row = gid >> 5;                          // ((layer*256+h)*64)+comp
        int comp = row & 63, h = (row >> 6) & 255, layer = row >> 14;
        int n = comp >> 1, isIm = comp & 1;
        float4 q = s4param(log_dt, A_re_log, A_im, B_re, B_im, C_re, C_im, layer, h, n);
        unsigned int vpk = 0, mpk = 0;
#pragma unroll
        for (int e = 0; e < 2; ++e) {
            int j = jp + e;
            float dv = (float)(63 - j);
            float magv = __expf(dv * q.x);
            float pr = dv * q.y * inv2pi;
            float th = (pr - floorf(pr)) * twopi;
            float c = __cosf(th), s = __sinf(th);
            float vre = magv * (q.z * c - q.w * s);
            float vim = magv * (q.z * s + q.w * c);
            vpk |= (unsigned int)f2bu(isIm ? vim : vre) << (16 * e);
            float dm = (float)(j + 1);
            float magm = __expf(dm * q.x);
            float pr2 = dm * q.y * inv2pi;
            float th2 = (pr2 - floorf(pr2)) * twopi;
            float mv = isIm ? (-2.f * magm * __sinf(th2)) : (2.f * magm * __cosf(th2));
            mpk |= (unsigned int)f2bu(mv) << (16 * e);
        }
        // V fragment-major within (layer,h) 64x64 block
        {
            int mtv = comp >> 4, frv = comp & 15;
            int ksv = jp >> 5, qdv = (jp >> 3) & 3, ev = jp & 7;
            size_t voff = (size_t)(layer * 256 + h) * 4096
                        + ((size_t)((mtv * 2 + ksv) * 64) + qdv * 16 + frv) * 8 + ev;
            ((unsigned int*)Vg)[voff >> 1] = vpk;    // jp even -> voff even
        }
        ((unsigned int*)Mg)[(size_t)row * 32 + (jp >> 1)] = mpk;   // M row-major (LDS-staged)
    } else if (bx < VMB_ + TDB_) {                   // Td
        int gid = (bx - VMB_) * 256 + threadIdx.x;
        int d = gid % 66;
        int lh = gid / 66;
        if (lh < NLAYERS * HDIM && d < 65) {
            int layer = lh >> 8, h = lh & 255;
            float fd = (float)d;
            float acc = 0.f;
            for (int n = 0; n < NSTATE; ++n) {
                float4 q = s4param(log_dt, A_re_log, A_im, B_re, B_im, C_re, C_im, layer, h, n);
                float mag = __expf(fd * q.x);
                float pr = fd * q.y * inv2pi;
                float th = (pr - floorf(pr)) * twopi;
                acc += mag * (q.z * __cosf(th) - q.w * __sinf(th));
            }
            Td[(size_t)lh * 66 + d] = 2.f * acc;
        }
    } else if (bx < VMB_ + TDB_ + PAB_) {            // PA64 = dA^64 per (layer,n,h)
        int idx = (bx - VMB_ - TDB_) * 256 + threadIdx.x;
        int h = idx & 255, n = (idx >> 8) & 31, layer = idx >> 13;
        float4 q = s4param(log_dt, A_re_log, A_im, B_re, B_im, C_re, C_im, layer, h, n);
        float e64 = expf(64.0f * q.x);
        float ph  = 64.0f * q.y;
        PA64[idx] = make_float2(e64 * cosf(ph), e64 * sinf(ph));
    } else if (bx < VMB_ + TDB_ + PAB_ + WCB_) {     // Wt fragment-major
        int idx = (bx - VMB_ - TDB_ - PAB_) * 256 + threadIdx.x;
        int k = idx & 255;
        int n = (idx >> 8) & 511;
        int layer = idx >> 17;
        // [nb=n>>4][ks=k>>5][quad=(k>>3)&3][fr=n&15][e=k&7]
        size_t off = (size_t)layer * (512 * 256)
                   + ((size_t)((n >> 4) * 8 + (k >> 5)) * 64 + (((k >> 3) & 3) * 16 + (n & 15))) * 8
                   + (k & 7);
        Wt[off] = __float2bfloat16(out_w[((size_t)(layer * 256 + k)) * 512 + n]);
    } else {                                         // Wet transpose
        int idx = (bx - VMB_ - TDB_ - PAB_ - WCB_) * 256 + threadIdx.x;
        int k = idx & 127, n = idx >> 7;
        Wet[idx] = __float2bfloat16(enc_w[(size_t)k * HDIM + n]);
    }
}

// ---------------- encoder GEMM (bf16 MFMA): H(bf16) = X@We + b, + transposed Ut ----------------
__global__ __launch_bounds__(256) void k_enc2(const float* __restrict__ X, const bf16* __restrict__ Wet,
                                              const float* __restrict__ bias, bf16* __restrict__ H,
                                              bf16* __restrict__ Ut) {
    __shared__ bf16 A_s[128 * 136];
    __shared__ bf16 B_s[64 * 136];
    int tid = threadIdx.x;
    int lane = tid & 63, wv = tid >> 6, quad = lane >> 4, fr = lane & 15;
    int m0 = blockIdx.x * 128, n0 = blockIdx.y * 64;
#pragma unroll
    for (int i = 0; i < 16; ++i) {               // stage X fp32 -> bf16 [m][k]
        int q = tid + i * 256, row = q >> 5, seg = q & 31;
        float4 v = *(const float4*)&X[(size_t)(m0 + row) * DIN + seg * 4];
        bf16* dst = &A_s[row * 136 + seg * 4];
        dst[0] = __float2bfloat16(v.x); dst[1] = __float2bfloat16(v.y);
        dst[2] = __float2bfloat16(v.z); dst[3] = __float2bfloat16(v.w);
    }
#pragma unroll
    for (int i = 0; i < 4; ++i) {                // stage Wet [n][k]
        int q = tid + i * 256, row = q >> 4, seg = q & 15;
        *(uint4*)&B_s[row * 136 + seg * 8] = *(const uint4*)&Wet[(size_t)(n0 + row) * DIN + seg * 8];
    }
    __syncthreads();
    f32x4 acc[2][4];
#pragma unroll
    for (int mt = 0; mt < 2; ++mt)
#pragma unroll
        for (int nt = 0; nt < 4; ++nt) acc[mt][nt] = (f32x4){0.f, 0.f, 0.f, 0.f};
#pragma unroll
    for (int ks = 0; ks < 4; ++ks) {
        bf16x8 a[2], b[4];
#pragma unroll
        for (int mt = 0; mt < 2; ++mt)
            a[mt] = *(const bf16x8*)&A_s[(wv * 32 + mt * 16 + fr) * 136 + ks * 32 + quad * 8];
#pragma unroll
        for (int nt = 0; nt < 4; ++nt)
            b[nt] = *(const bf16x8*)&B_s[(nt * 16 + fr) * 136 + ks * 32 + quad * 8];
#pragma unroll
        for (int mt = 0; mt < 2; ++mt)
#pragma unroll
            for (int nt = 0; nt < 4; ++nt)
                acc[mt][nt] = __builtin_amdgcn_mfma_f32_16x16x32_bf16(a[mt], b[nt], acc[mt][nt], 0, 0, 0);
    }
    __syncthreads();                             // B_s reuse as transpose bounce
#pragma unroll
    for (int mt = 0; mt < 2; ++mt)
#pragma unroll
        for (int nt = 0; nt < 4; ++nt) {
            int n = n0 + nt * 16 + fr;
            float bv = bias[n];
#pragma unroll
            for (int r = 0; r < 4; ++r) {
                int m = m0 + wv * 32 + mt * 16 + quad * 4 + r;
                float hv = acc[mt][nt][r] + bv;
                bf16 hb = __float2bfloat16(hv);
                H[(size_t)m * HDIM + n] = hb;
                B_s[(nt * 16 + fr) * 136 + (wv * 32 + mt * 16 + quad * 4 + r)] = hb;
            }
        }
    __syncthreads();
#pragma unroll
    for (int i = 0; i < 4; ++i) {                // coalesced Ut store [h][m]
        int q = tid + i * 256, row = q >> 4, seg = q & 15;
        *(uint4*)&Ut[(size_t)(n0 + row) * M_ROWS + m0 + seg * 8] = *(uint4*)&B_s[row * 136 + seg * 8];
    }
}

// ---------------- fused conv ----------------
// r6: packed u32 Toeplitz fill; epilogue u-gathers hoisted before 2nd MFMA loop; 2nd loop
// A/B fragments register-pipelined one ks ahead (hides ~120cy ds_read latency per step);
// rcp-based sigmoid in GELU.
__global__ __launch_bounds__(256) void k_conv(const bf16* __restrict__ Ut,
                                              const bf16* __restrict__ Vg,
                                              const bf16* __restrict__ Mg,
                                              const float* __restrict__ Tdl,
                                              const float2* __restrict__ PA,
                                              const float* __restrict__ Dw,
                                              bf16* __restrict__ Yt) {
    __shared__ bf16 A_s[64 * 136];               // [l][k2], k2<64: T, k2>=64: M
    __shared__ bf16 Eo_s[128 * 72];              // [bc][comp]: E, then carries, then o_s
    int h = blockIdx.x, bc0 = blockIdx.y * 128;
    int tid = threadIdx.x;
    int lane = tid & 63, wv = tid >> 6, quad = lane >> 4, fr = lane & 15;
    const float* Tdh = Tdl + (size_t)h * 66;
    const bf16* Uh = Ut + (size_t)h * M_ROWS + (size_t)bc0 * 64;
    // hoist ALL E-phase global fragments first (12 independent loads, batched issue)
    bf16x8 va[2][4], ub[2][2];
#pragma unroll
    for (int ks = 0; ks < 2; ++ks) {
#pragma unroll
        for (int mt = 0; mt < 4; ++mt)           // fragment-major Vg: coalesced
            va[ks][mt] = *(const bf16x8*)&Vg[(size_t)h * 4096 + ((size_t)((mt * 2 + ks) * 64) + lane) * 8];
#pragma unroll
        for (int nf = 0; nf < 2; ++nf)
            ub[ks][nf] = *(const bf16x8*)&Uh[(size_t)(wv * 32 + nf * 16 + fr) * 64 + ks * 32 + quad * 8];
    }
#pragma unroll
    for (int i = 0; i < 2; ++i) {                // stage M transposed into A_s cols 64..127
        int q = tid + i * 256, comp = q >> 3, seg = q & 7;
        uint4 v = *(const uint4*)&Mg[((size_t)h * 64 + comp) * 64 + seg * 8];
        const bf16* pv = (const bf16*)&v;
#pragma unroll
        for (int e = 0; e < 8; ++e) A_s[(seg * 8 + e) * 136 + 64 + comp] = pv[e];
    }
#pragma unroll
    for (int i = 0; i < 8; ++i) {                // Toeplitz T fill, packed u32 writes
        int q = tid + i * 256;                   // q in [0,2048): l = q>>5, jp = (q&31)*2
        int l = q >> 5, jp = (q & 31) * 2;
        int d0 = l - jp, d1 = d0 - 1;
        unsigned int pk = (unsigned int)f2bu(d0 >= 0 ? Tdh[d0] : 0.f)
                        | ((unsigned int)f2bu(d1 >= 0 ? Tdh[d1] : 0.f) << 16);
        *(unsigned int*)&A_s[l * 136 + jp] = pk;
    }
    f32x4 eacc[4][2];
#pragma unroll
    for (int mt = 0; mt < 4; ++mt)
#pragma unroll
        for (int nf = 0; nf < 2; ++nf) eacc[mt][nf] = (f32x4){0.f, 0.f, 0.f, 0.f};
#pragma unroll
    for (int ks = 0; ks < 2; ++ks)
#pragma unroll
        for (int mt = 0; mt < 4; ++mt)
#pragma unroll
            for (int nf = 0; nf < 2; ++nf)
                eacc[mt][nf] = __builtin_amdgcn_mfma_f32_16x16x32_bf16(va[ks][mt], ub[ks][nf], eacc[mt][nf], 0, 0, 0);
#pragma unroll
    for (int mt = 0; mt < 4; ++mt)               // E -> Eo_s [bc][comp], packed pairs
#pragma unroll
        for (int nf = 0; nf < 2; ++nf) {
            int bc = wv * 32 + nf * 16 + fr;
#pragma unroll
            for (int r = 0; r < 4; r += 2) {
                int comp = mt * 16 + quad * 4 + r;
                *(unsigned int*)&Eo_s[bc * 72 + comp] =
                    (unsigned int)f2bu(eacc[mt][nf][r]) | ((unsigned int)f2bu(eacc[mt][nf][r + 1]) << 16);
            }
        }
    __syncthreads();                             // Eo + A_s ready
    {                                            // in-place carry scan: thread = (b_local, n)
        int bl = tid >> 5, n = tid & 31;
        float2 a = PA[n * HDIM + h];
        float cr = 0.f, ci = 0.f;
#pragma unroll
        for (int c = 0; c < NCH; ++c) {
            int bc = bl * NCH + c;
            unsigned int* slot = (unsigned int*)&Eo_s[bc * 72 + 2 * n];
            unsigned int ev = *slot;
            *slot = (unsigned int)f2bu(cr) | ((unsigned int)f2bu(ci) << 16);
            float er = bu2f((unsigned short)(ev & 0xffff));
            float ei = bu2f((unsigned short)(ev >> 16));
            float nr = fmaf(a.x, cr, fmaf(-a.y, ci, er));
            ci = fmaf(a.x, ci, fmaf(a.y, cr, ei));
            cr = nr;
        }
    }
    __syncthreads();                             // carries in Eo_s
    // prefetch epilogue u-gathers (independent of MFMA results; L2-hot)
    uint2 uvp[4][2];
#pragma unroll
    for (int mt = 0; mt < 4; ++mt)
#pragma unroll
        for (int nf = 0; nf < 2; ++nf)
            uvp[mt][nf] = *(const uint2*)&Uh[(size_t)(wv * 32 + nf * 16 + fr) * 64 + mt * 16 + quad * 4];
    f32x4 acc[4][2];
#pragma unroll
    for (int mt = 0; mt < 4; ++mt)
#pragma unroll
        for (int nf = 0; nf < 2; ++nf) acc[mt][nf] = (f32x4){0.f, 0.f, 0.f, 0.f};

#define LDAB(AA, BB, KS) do { \
    _Pragma("unroll") \
    for (int mt = 0; mt < 4; ++mt) \
        AA[mt] = *(const bf16x8*)&A_s[(mt * 16 + fr) * 136 + (KS) * 32 + quad * 8]; \
    _Pragma("unroll") \
    for (int nf = 0; nf < 2; ++nf) \
        BB[nf] = ((KS) < 2) ? ub[(KS) & 1][nf] \
               : *(const bf16x8*)&Eo_s[(wv * 32 + nf * 16 + fr) * 72 + ((KS) & 1) * 32 + quad * 8]; \
    } while (0)
#define MFMAC(AA, BB) do { \
    _Pragma("unroll") \
    for (int mt = 0; mt < 4; ++mt) \
        _Pragma("unroll") \
        for (int nf = 0; nf < 2; ++nf) \
            acc[mt][nf] = __builtin_amdgcn_mfma_f32_16x16x32_bf16(AA[mt], BB[nf], acc[mt][nf], 0, 0, 0); \
    } while (0)

    {
        bf16x8 aA[4], bA[2], aB[4], bB[2];
        LDAB(aA, bA, 0);
        LDAB(aB, bB, 1);
        MFMAC(aA, bA);
        LDAB(aA, bA, 2);
        MFMAC(aB, bB);
        LDAB(aB, bB, 3);
        MFMAC(aA, bA);
        MFMAC(aB, bB);
    }
#undef LDAB
#undef MFMAC

    float Dv = Dw[h];
#pragma unroll
    for (int mt = 0; mt < 4; ++mt)
#pragma unroll
        for (int nf = 0; nf < 2; ++nf) {
            int bcl = wv * 32 + nf * 16 + fr;
            const bf16* up = (const bf16*)&uvp[mt][nf];
#pragma unroll
            for (int r = 0; r < 4; ++r) {
                int l = mt * 16 + quad * 4 + r;
                float u = __bfloat162float(up[r]);
                float v = fmaf(Dv, u, acc[mt][nf][r]);
                float z2 = 1.5957691216057308f * (v + 0.044715f * v * v * v);
                float sg = __builtin_amdgcn_rcpf(1.f + __expf(-z2));
                Eo_s[bcl * 72 + l] = __float2bfloat16(v * sg);
            }
        }
    __syncthreads();
#pragma unroll
    for (int i = 0; i < 4; ++i) {                // coalesced Yt store
        int q = tid + i * 256, row = q >> 3, c8 = q & 7;
        *(uint4*)&Yt[(size_t)h * M_ROWS + (size_t)(bc0 + row) * 64 + c8 * 8] =
            *(uint4*)&Eo_s[row * 72 + c8 * 8];
    }
}

// ---------------- FUSED output GEMM + GLU + residual + LayerNorm (+ decoder on last layer) ----
// r6 = r4 structure (grid 1024, m=32, LDS 21.3KB) +
//   (a) A-fragment register pipeline paired with the B p/q double-buffer
//   (b) Hb residual prefetched at kernel start (consumed ~3000cy later in LN)
//   (c) v_rcp_f32 sigmoid
__global__ __launch_bounds__(256) void k_gluln(const bf16* __restrict__ Yt,
                                               const bf16* __restrict__ Wt,
                                               const float* __restrict__ wb,
                                               bf16* __restrict__ Hb,
                                               const float* __restrict__ w,
                                               const float* __restrict__ bbias,
                                               bf16* __restrict__ Ut,
                                               const float* __restrict__ dw,
                                               const float* __restrict__ db,
                                               float* __restrict__ outp, int mode) {
    __shared__ __align__(16) bf16 A_s[32 * 264];   // A tile [m][k]; then g [m][n]; mode1: dw overlay
    __shared__ float red[2][8][32];
    __shared__ float stat[2][32];
    __shared__ float w_s[256], b_s[256];
    __shared__ float db_s[16];
    int tid = threadIdx.x;
    int lane = tid & 63, wv = tid >> 6;
    int quad = lane >> 4, fr = lane & 15;
    int m0 = blockIdx.x * 32;
    int rr = tid & 31, qd = tid >> 5;
    w_s[tid] = w[tid]; b_s[tid] = bbias[tid];
    if (mode == 1 && tid < DOUT) db_s[tid] = db[tid];
    float bias1[4], bias2[4];
#pragma unroll
    for (int nt = 0; nt < 4; ++nt) {             // GLU biases -> regs (L2-hot)
        bias1[nt] = wb[wv * 64 + nt * 16 + fr];
        bias2[nt] = wb[HDIM + wv * 64 + nt * 16 + fr];
    }
    // A-stage loads (Yt, cross-XCD) + Hb residual prefetch (consumed in LN)
    int mg = tid & 7, hg = tid >> 3;             // mg: 4-m group; hg: k-octet [0,32)
    uint2 rowv[8];
#pragma unroll
    for (int e = 0; e < 8; ++e)
        rowv[e] = *(const uint2*)&Yt[(size_t)(hg * 8 + e) * M_ROWS + m0 + mg * 4];
    uint4 hbv[4];
#pragma unroll
    for (int i = 0; i < 4; ++i)
        hbv[i] = *(const uint4*)&Hb[(size_t)(m0 + rr) * HDIM + qd * 32 + i * 8];
    {                                            // pack A: Yt[k][m] -> A_s[m][k] (reg transpose)
#pragma unroll
        for (int j = 0; j < 4; ++j) {
            unsigned int pk[4];
#pragma unroll
            for (int k2 = 0; k2 < 4; ++k2) {
                unsigned int lo = ((const unsigned short*)&rowv[2 * k2])[j];
                unsigned int hi = ((const unsigned short*)&rowv[2 * k2 + 1])[j];
                pk[k2] = lo | (hi << 16);
            }
            *(uint4*)&A_s[(mg * 4 + j) * 264 + hg * 8] = *(uint4*)pk;
        }
    }
    f32x4 acc1[2][4], acc2[2][4];
#pragma unroll
    for (int mt = 0; mt < 2; ++mt)
#pragma unroll
        for (int nt = 0; nt < 4; ++nt) {
            acc1[mt][nt] = (f32x4){0.f, 0.f, 0.f, 0.f};
            acc2[mt][nt] = (f32x4){0.f, 0.f, 0.f, 0.f};
        }
    __syncthreads();

#define LOAD_B(d1, d2, KS) do { \
    _Pragma("unroll") \
    for (int nt = 0; nt < 4; ++nt) { \
        d1[nt] = *(const bf16x8*)&Wt[((size_t)((wv * 4 + nt) * 8 + (KS)) * 64 + lane) * 8]; \
        d2[nt] = *(const bf16x8*)&Wt[((size_t)((16 + wv * 4 + nt) * 8 + (KS)) * 64 + lane) * 8]; \
    } } while (0)

#define LOAD_A(da, KS) do { \
    _Pragma("unroll") \
    for (int mt = 0; mt < 2; ++mt) \
        da[mt] = *(const bf16x8*)&A_s[(mt * 16 + fr) * 264 + (KS) * 32 + quad * 8]; \
    } while (0)

#define MFMA8(da, bb1, bb2) do { \
    _Pragma("unroll") \
    for (int mt = 0; mt < 2; ++mt) \
        _Pragma("unroll") \
        for (int nt = 0; nt < 4; ++nt) { \
            acc1[mt][nt] = __builtin_amdgcn_mfma_f32_16x16x32_bf16(da[mt], bb1[nt], acc1[mt][nt], 0, 0, 0); \
            acc2[mt][nt] = __builtin_amdgcn_mfma_f32_16x16x32_bf16(da[mt], bb2[nt], acc2[mt][nt], 0, 0, 0); \
        } } while (0)

    {
        bf16x8 p1[4], p2[4], q1[4], q2[4], aP[2], aQ[2];
        LOAD_B(p1, p2, 0); LOAD_A(aP, 0);
#pragma unroll
        for (int kp = 0; kp < 4; ++kp) {
            LOAD_B(q1, q2, 2 * kp + 1); LOAD_A(aQ, 2 * kp + 1);
            MFMA8(aP, p1, p2);
            if (kp < 3) { LOAD_B(p1, p2, 2 * kp + 2); LOAD_A(aP, 2 * kp + 2); }
            MFMA8(aQ, q1, q2);
        }
    }
#undef LOAD_B
#undef LOAD_A
#undef MFMA8

    __syncthreads();                             // A_s dead as A-tile; reuse for g [m][n]
#pragma unroll
    for (int mt = 0; mt < 2; ++mt)
#pragma unroll
        for (int nt = 0; nt < 4; ++nt) {
            int n = wv * 64 + nt * 16 + fr;
#pragma unroll
            for (int r = 0; r < 4; ++r) {
                int m = mt * 16 + quad * 4 + r;
                float z1 = acc1[mt][nt][r] + bias1[nt];
                float z2 = acc2[mt][nt][r] + bias2[nt];
                float sg = __builtin_amdgcn_rcpf(1.0f + __expf(-z2));
                A_s[m * 264 + n] = __float2bfloat16(z1 * sg);
            }
        }
    __syncthreads();                             // g complete
    float rv[32];
    float sum = 0.f, sq = 0.f;
#pragma unroll
    for (int i4 = 0; i4 < 4; ++i4) {
        uint4 gv = *(uint4*)&A_s[rr * 264 + qd * 32 + i4 * 8];
        const bf16* gp = (const bf16*)&gv;
        const bf16* hp = (const bf16*)&hbv[i4];
#pragma unroll
        for (int e = 0; e < 8; ++e) {
            float v = __bfloat162float(gp[e]) + __bfloat162float(hp[e]);
            rv[i4 * 8 + e] = v; sum += v; sq += v * v;
        }
    }
    red[0][qd][rr] = sum; red[1][qd][rr] = sq;
    __syncthreads();
    if (tid < 32) {
        float s = 0.f, s2 = 0.f;
#pragma unroll
        for (int q = 0; q < 8; ++q) { s += red[0][q][tid]; s2 += red[1][q][tid]; }
        float mean = s * (1.f / HDIM);
        float var = s2 * (1.f / HDIM) - mean * mean;
        stat[0][tid] = mean; stat[1][tid] = rsqrtf(var + 1e-5f);
    }
    __syncthreads();
    float mean = stat[0][rr], rstd = stat[1][rr];
#pragma unroll
    for (int j = 0; j < 32; ++j)
        rv[j] = (rv[j] - mean) * rstd * w_s[qd * 32 + j] + b_s[qd * 32 + j];
    if (mode == 0) {
        // packed bf16 H write (new residual = LN out)
        bf16* Hw = Hb + (size_t)(m0 + rr) * HDIM + qd * 32;
#pragma unroll
        for (int j = 0; j < 32; j += 8) {
            unsigned int pk[4];
#pragma unroll
            for (int e = 0; e < 4; ++e)
                pk[e] = (unsigned int)f2bu(rv[j + 2 * e]) | ((unsigned int)f2bu(rv[j + 2 * e + 1]) << 16);
            *(uint4*)&Hw[j] = *(uint4*)pk;
        }
        // direct Ut store: [h][m], lanes rr contiguous -> 64B/line per store inst
        bf16* Up = Ut + (size_t)(qd * 32) * M_ROWS + m0 + rr;
#pragma unroll
        for (int j = 0; j < 32; ++j)
            Up[(size_t)j * M_ROWS] = __float2bfloat16(rv[j]);
    } else {
        // decoder: stage dec_w over dead A_s (all A_s reads completed 2 barriers ago)
        float* dwf = (float*)A_s;                // 2560 floats = 10240 B <= 16896 B
        for (int e = tid; e < HDIM * DOUT; e += 256) dwf[e] = dw[e];
        __syncthreads();
        float part[DOUT];
#pragma unroll
        for (int o = 0; o < DOUT; ++o) part[o] = 0.f;
#pragma unroll
        for (int j = 0; j < 32; ++j) {
            float tv = rv[j];
            const float* dr = &dwf[(qd * 32 + j) * DOUT];
#pragma unroll
            for (int o = 0; o < DOUT; ++o) part[o] = fmaf(tv, dr[o], part[o]);
        }
        // reduce across the 8 qd-groups, 2 outputs per pass via red
#pragma unroll
        for (int oc = 0; oc < 5; ++oc) {
            red[0][qd][rr] = part[2 * oc];
            red[1][qd][rr] = part[2 * oc + 1];
            __syncthreads();
            if (tid < 64) {
                int rl = tid & 31, ph = tid >> 5;
                float s = 0.f;
#pragma unroll
                for (int q = 0; q < 8; ++q) s += red[ph][q][rl];
                int o = 2 * oc + ph;
                outp[(size_t)(m0 + rl) * DOUT + o] = s + db_s[o];
            }
            __syncthreads();
        }
    }
}

extern "C" void kernel_launch(void* const* d_in, const int* in_sizes, int n_in,
                              void* d_out, int out_size, void* d_ws, size_t ws_size,
                              hipStream_t stream) {
    const float* x        = (const float*)d_in[0];
    const float* enc_w    = (const float*)d_in[1];
    const float* enc_b    = (const float*)d_in[2];
    const float* log_dt   = (const float*)d_in[3];
    const float* A_re_log = (const float*)d_in[4];
    const float* A_im     = (const float*)d_in[5];
    const float* B_re     = (const float*)d_in[6];
    const float* B_im     = (const float*)d_in[7];
    const float* C_re     = (const float*)d_in[8];
    const float* C_im     = (const float*)d_in[9];
    const float* Dp       = (const float*)d_in[10];
    const float* ln_w     = (const float*)d_in[11];
    const float* ln_b     = (const float*)d_in[12];
    const float* out_w    = (const float*)d_in[13];
    const float* out_b    = (const float*)d_in[14];
    const float* dec_w    = (const float*)d_in[15];
    const float* dec_b    = (const float*)d_in[16];
    float* outp = (float*)d_out;

    float* w = (float*)d_ws;
    const size_t PWE = (size_t)NLAYERS * NSTATE * HDIM;   // 32768
    const size_t MH  = (size_t)M_ROWS * HDIM;             // 8388608
    const size_t VME = (size_t)NLAYERS * HDIM * 64 * 64;  // 4M elems/matrix
    float2* PA64 = (float2*)(w + 4 * PWE);                // 256 KB
    float*  Td   = w + 6 * PWE;                           // 270 KB
    bf16*   Hbuf = (bf16*)(Td + (size_t)NLAYERS * HDIM * 66);  // 16.7 MB bf16
    bf16*   Ut   = Hbuf + MH;                             // 16.7 MB
    bf16*   Yt   = Ut + MH;                               // 16.7 MB
    bf16*   Wt   = Yt + MH;                               // 1 MB (G buffer eliminated)
    bf16*   Wet  = Wt + (size_t)NLAYERS * 512 * HDIM;     // 64 KB
    bf16*   Vg   = Wet + (size_t)HDIM * DIN;              // 8 MB (all layers)
    bf16*   Mg   = Vg + VME;                              // 8 MB (all layers)

    {
        int total = VMB_ + TDB_ + PAB_ + WCB_ + HDIM * DIN / 256;
        k_setup<<<total, 256, 0, stream>>>(log_dt, A_re_log, A_im, B_re, B_im, C_re, C_im,
                                           out_w, enc_w, Td, Vg, Mg, PA64, Wt, Wet);
    }

    dim3 ge(M_ROWS / 128, HDIM / 64);
    k_enc2<<<ge, 256, 0, stream>>>(x, Wet, enc_b, Hbuf, Ut);

    dim3 gconv(HDIM, NBC / 128);
    for (int layer = 0; layer < NLAYERS; ++layer) {
        const float2* pal = PA64 + (size_t)layer * NSTATE * HDIM;
        const float*  tdl = Td + (size_t)layer * HDIM * 66;
        const bf16*   vgl = Vg + (size_t)layer * HDIM * 64 * 64;
        const bf16*   mgl = Mg + (size_t)layer * HDIM * 64 * 64;
        k_conv<<<gconv, 256, 0, stream>>>(Ut, vgl, mgl, tdl, pal, Dp + layer * HDIM, Yt);
        k_gluln<<<M_ROWS / 32, 256, 0, stream>>>(Yt, Wt + (size_t)layer * 512 * HDIM,
                                                 out_b + layer * 2 * HDIM, Hbuf,
                                                 ln_w + layer * HDIM, ln_b + layer * HDIM,
                                                 Ut, dec_w, dec_b, outp,
                                                 layer == NLAYERS - 1 ? 1 : 0);
    }
}

// Round 7
// 296.989 us; speedup vs baseline: 1.1853x; 1.0802x over previous
//
#include <hip/hip_runtime.h>
#include <hip/hip_bf16.h>
#include <math.h>

#define B_SZ    32
#define LSEQ    1024
#define DIN     128
#define HDIM    256
#define NLAYERS 4
#define NSTATE  32
#define DOUT    10
#define M_ROWS  (B_SZ*LSEQ)   // 32768
#define CH      64            // scan chunk length
#define NCH     (LSEQ/CH)     // 16 chunks
#define NBC     (B_SZ*NCH)    // 512 chunk-columns

typedef __hip_bfloat16 bf16;
typedef __attribute__((ext_vector_type(8))) short bf16x8;
typedef __attribute__((ext_vector_type(4))) float f32x4;

__device__ __forceinline__ unsigned short f2bu(float x) {
    bf16 b = __float2bfloat16(x);
    return *(unsigned short*)&b;
}
__device__ __forceinline__ float bu2f(unsigned short u) {
    bf16 b = *(bf16*)&u;
    return __bfloat162float(b);
}

// inline S4D discretization: returns (dtAre, dtAim, Wre, Wim)
__device__ __forceinline__ float4 s4param(const float* __restrict__ log_dt,
                                          const float* __restrict__ A_re_log,
                                          const float* __restrict__ A_im,
                                          const float* __restrict__ B_re,
                                          const float* __restrict__ B_im,
                                          const float* __restrict__ C_re,
                                          const float* __restrict__ C_im,
                                          int layer, int h, int n) {
    int hn = layer * HDIM + h;
    int idx = hn * NSTATE + n;
    float dt   = expf(log_dt[hn]);
    float Are  = -expf(A_re_log[idx]);
    float Aim  = A_im[idx];
    float dtAre = dt * Are, dtAim = dt * Aim;
    float ea   = expf(dtAre);
    float dAre = ea * cosf(dtAim), dAim = ea * sinf(dtAim);
    float nre = dAre - 1.0f, nim = dAim;
    float inv = 1.0f / (Are * Are + Aim * Aim);
    float tre = (nre * Are + nim * Aim) * inv;
    float tim = (nim * Are - nre * Aim) * inv;
    float Brv = B_re[idx], Biv = B_im[idx];
    float dBre = Brv * tre - Biv * tim;
    float dBim = Brv * tim + Biv * tre;
    float Crv = C_re[idx], Civ = C_im[idx];
    float Wre = Crv * dBre - Civ * dBim;
    float Wim = Crv * dBim + Civ * dBre;
    return make_float4(dtAre, dtAim, Wre, Wim);
}

// ---------------- ONE setup kernel: V/M, Td, PA64, weight transposes ----------------
// r3: Vg and Wt stored FRAGMENT-MAJOR so consumer wave-loads are base+lane*16B coalesced.
#define VMB_ (NLAYERS*HDIM*64*32/256)    // 8192
#define TDB_ ((NLAYERS*HDIM*66+255)/256) // 264
#define PAB_ (NLAYERS*NSTATE*HDIM/256)   // 128
#define WCB_ (NLAYERS*512*256/256)       // 2048
__global__ void k_setup(const float* __restrict__ log_dt, const float* __restrict__ A_re_log,
                        const float* __restrict__ A_im, const float* __restrict__ B_re,
                        const float* __restrict__ B_im, const float* __restrict__ C_re,
                        const float* __restrict__ C_im, const float* __restrict__ out_w,
                        const float* __restrict__ enc_w, float* __restrict__ Td,
                        bf16* __restrict__ Vg, bf16* __restrict__ Mg,
                        float2* __restrict__ PA64, bf16* __restrict__ Wt,
                        bf16* __restrict__ Wet) {
    const float inv2pi = 0.15915494309189535f;
    const float twopi  = 6.283185307179586f;
    int bx = blockIdx.x;
    if (bx < VMB_) {                                 // V/M pair-elements
        int gid = bx * 256 + threadIdx.x;
        int jp = (gid & 31) * 2;
        int row = gid >> 5;                          // ((layer*256+h)*64)+comp
        int comp = row & 63, h = (row >> 6) & 255, layer = row >> 14;
        int n = comp >> 1, isIm = comp & 1;
        float4 q = s4param(log_dt, A_re_log, A_im, B_re, B_im, C_re, C_im, layer, h, n);
        unsigned int vpk = 0, mpk = 0;
#pragma unroll
        for (int e = 0; e < 2; ++e) {
            int j = jp + e;
            float dv = (float)(63 - j);
            float magv = __expf(dv * q.x);
            float pr = dv * q.y * inv2pi;
            float th = (pr - floorf(pr)) * twopi;
            float c = __cosf(th), s = __sinf(th);
            float vre = magv * (q.z * c - q.w * s);
            float vim = magv * (q.z * s + q.w * c);
            vpk |= (unsigned int)f2bu(isIm ? vim : vre) << (16 * e);
            float dm = (float)(j + 1);
            float magm = __expf(dm * q.x);
            float pr2 = dm * q.y * inv2pi;
            float th2 = (pr2 - floorf(pr2)) * twopi;
            float mv = isIm ? (-2.f * magm * __sinf(th2)) : (2.f * magm * __cosf(th2));
            mpk |= (unsigned int)f2bu(mv) << (16 * e);
        }
        // V fragment-major within (layer,h) 64x64 block
        {
            int mtv = comp >> 4, frv = comp & 15;
            int ksv = jp >> 5, qdv = (jp >> 3) & 3, ev = jp & 7;
            size_t voff = (size_t)(layer * 256 + h) * 4096
                        + ((size_t)((mtv * 2 + ksv) * 64) + qdv * 16 + frv) * 8 + ev;
            ((unsigned int*)Vg)[voff >> 1] = vpk;    // jp even -> voff even
        }
        ((unsigned int*)Mg)[(size_t)row * 32 + (jp >> 1)] = mpk;   // M row-major (LDS-staged)
    } else if (bx < VMB_ + TDB_) {                   // Td
        int gid = (bx - VMB_) * 256 + threadIdx.x;
        int d = gid % 66;
        int lh = gid / 66;
        if (lh < NLAYERS * HDIM && d < 65) {
            int layer = lh >> 8, h = lh & 255;
            float fd = (float)d;
            float acc = 0.f;
            for (int n = 0; n < NSTATE; ++n) {
                float4 q = s4param(log_dt, A_re_log, A_im, B_re, B_im, C_re, C_im, layer, h, n);
                float mag = __expf(fd * q.x);
                float pr = fd * q.y * inv2pi;
                float th = (pr - floorf(pr)) * twopi;
                acc += mag * (q.z * __cosf(th) - q.w * __sinf(th));
            }
            Td[(size_t)lh * 66 + d] = 2.f * acc;
        }
    } else if (bx < VMB_ + TDB_ + PAB_) {            // PA64 = dA^64 per (layer,n,h)
        int idx = (bx - VMB_ - TDB_) * 256 + threadIdx.x;
        int h = idx & 255, n = (idx >> 8) & 31, layer = idx >> 13;
        float4 q = s4param(log_dt, A_re_log, A_im, B_re, B_im, C_re, C_im, layer, h, n);
        float e64 = expf(64.0f * q.x);
        float ph  = 64.0f * q.y;
        PA64[idx] = make_float2(e64 * cosf(ph), e64 * sinf(ph));
    } else if (bx < VMB_ + TDB_ + PAB_ + WCB_) {     // Wt fragment-major
        int idx = (bx - VMB_ - TDB_ - PAB_) * 256 + threadIdx.x;
        int k = idx & 255;
        int n = (idx >> 8) & 511;
        int layer = idx >> 17;
        // [nb=n>>4][ks=k>>5][quad=(k>>3)&3][fr=n&15][e=k&7]
        size_t off = (size_t)layer * (512 * 256)
                   + ((size_t)((n >> 4) * 8 + (k >> 5)) * 64 + (((k >> 3) & 3) * 16 + (n & 15))) * 8
                   + (k & 7);
        Wt[off] = __float2bfloat16(out_w[((size_t)(layer * 256 + k)) * 512 + n]);
    } else {                                         // Wet transpose
        int idx = (bx - VMB_ - TDB_ - PAB_ - WCB_) * 256 + threadIdx.x;
        int k = idx & 127, n = idx >> 7;
        Wet[idx] = __float2bfloat16(enc_w[(size_t)k * HDIM + n]);
    }
}

// ---------------- encoder GEMM (bf16 MFMA): H(bf16) = X@We + b, + transposed Ut ----------------
__global__ __launch_bounds__(256) void k_enc2(const float* __restrict__ X, const bf16* __restrict__ Wet,
                                              const float* __restrict__ bias, bf16* __restrict__ H,
                                              bf16* __restrict__ Ut) {
    __shared__ bf16 A_s[128 * 136];
    __shared__ bf16 B_s[64 * 136];
    int tid = threadIdx.x;
    int lane = tid & 63, wv = tid >> 6, quad = lane >> 4, fr = lane & 15;
    int m0 = blockIdx.x * 128, n0 = blockIdx.y * 64;
#pragma unroll
    for (int i = 0; i < 16; ++i) {               // stage X fp32 -> bf16 [m][k]
        int q = tid + i * 256, row = q >> 5, seg = q & 31;
        float4 v = *(const float4*)&X[(size_t)(m0 + row) * DIN + seg * 4];
        bf16* dst = &A_s[row * 136 + seg * 4];
        dst[0] = __float2bfloat16(v.x); dst[1] = __float2bfloat16(v.y);
        dst[2] = __float2bfloat16(v.z); dst[3] = __float2bfloat16(v.w);
    }
#pragma unroll
    for (int i = 0; i < 4; ++i) {                // stage Wet [n][k]
        int q = tid + i * 256, row = q >> 4, seg = q & 15;
        *(uint4*)&B_s[row * 136 + seg * 8] = *(const uint4*)&Wet[(size_t)(n0 + row) * DIN + seg * 8];
    }
    __syncthreads();
    f32x4 acc[2][4];
#pragma unroll
    for (int mt = 0; mt < 2; ++mt)
#pragma unroll
        for (int nt = 0; nt < 4; ++nt) acc[mt][nt] = (f32x4){0.f, 0.f, 0.f, 0.f};
#pragma unroll
    for (int ks = 0; ks < 4; ++ks) {
        bf16x8 a[2], b[4];
#pragma unroll
        for (int mt = 0; mt < 2; ++mt)
            a[mt] = *(const bf16x8*)&A_s[(wv * 32 + mt * 16 + fr) * 136 + ks * 32 + quad * 8];
#pragma unroll
        for (int nt = 0; nt < 4; ++nt)
            b[nt] = *(const bf16x8*)&B_s[(nt * 16 + fr) * 136 + ks * 32 + quad * 8];
#pragma unroll
        for (int mt = 0; mt < 2; ++mt)
#pragma unroll
            for (int nt = 0; nt < 4; ++nt)
                acc[mt][nt] = __builtin_amdgcn_mfma_f32_16x16x32_bf16(a[mt], b[nt], acc[mt][nt], 0, 0, 0);
    }
    __syncthreads();                             // B_s reuse as transpose bounce
#pragma unroll
    for (int mt = 0; mt < 2; ++mt)
#pragma unroll
        for (int nt = 0; nt < 4; ++nt) {
            int n = n0 + nt * 16 + fr;
            float bv = bias[n];
#pragma unroll
            for (int r = 0; r < 4; ++r) {
                int m = m0 + wv * 32 + mt * 16 + quad * 4 + r;
                float hv = acc[mt][nt][r] + bv;
                bf16 hb = __float2bfloat16(hv);
                H[(size_t)m * HDIM + n] = hb;
                B_s[(nt * 16 + fr) * 136 + (wv * 32 + mt * 16 + quad * 4 + r)] = hb;
            }
        }
    __syncthreads();
#pragma unroll
    for (int i = 0; i < 4; ++i) {                // coalesced Ut store [h][m]
        int q = tid + i * 256, row = q >> 4, seg = q & 15;
        *(uint4*)&Ut[(size_t)(n0 + row) * M_ROWS + m0 + seg * 8] = *(uint4*)&B_s[row * 136 + seg * 8];
    }
}

// ---------------- fused conv (r6 version, unchanged) ----------------
__global__ __launch_bounds__(256) void k_conv(const bf16* __restrict__ Ut,
                                              const bf16* __restrict__ Vg,
                                              const bf16* __restrict__ Mg,
                                              const float* __restrict__ Tdl,
                                              const float2* __restrict__ PA,
                                              const float* __restrict__ Dw,
                                              bf16* __restrict__ Yt) {
    __shared__ bf16 A_s[64 * 136];               // [l][k2], k2<64: T, k2>=64: M
    __shared__ bf16 Eo_s[128 * 72];              // [bc][comp]: E, then carries, then o_s
    int h = blockIdx.x, bc0 = blockIdx.y * 128;
    int tid = threadIdx.x;
    int lane = tid & 63, wv = tid >> 6, quad = lane >> 4, fr = lane & 15;
    const float* Tdh = Tdl + (size_t)h * 66;
    const bf16* Uh = Ut + (size_t)h * M_ROWS + (size_t)bc0 * 64;
    // hoist ALL E-phase global fragments first (12 independent loads, batched issue)
    bf16x8 va[2][4], ub[2][2];
#pragma unroll
    for (int ks = 0; ks < 2; ++ks) {
#pragma unroll
        for (int mt = 0; mt < 4; ++mt)           // fragment-major Vg: coalesced
            va[ks][mt] = *(const bf16x8*)&Vg[(size_t)h * 4096 + ((size_t)((mt * 2 + ks) * 64) + lane) * 8];
#pragma unroll
        for (int nf = 0; nf < 2; ++nf)
            ub[ks][nf] = *(const bf16x8*)&Uh[(size_t)(wv * 32 + nf * 16 + fr) * 64 + ks * 32 + quad * 8];
    }
#pragma unroll
    for (int i = 0; i < 2; ++i) {                // stage M transposed into A_s cols 64..127
        int q = tid + i * 256, comp = q >> 3, seg = q & 7;
        uint4 v = *(const uint4*)&Mg[((size_t)h * 64 + comp) * 64 + seg * 8];
        const bf16* pv = (const bf16*)&v;
#pragma unroll
        for (int e = 0; e < 8; ++e) A_s[(seg * 8 + e) * 136 + 64 + comp] = pv[e];
    }
#pragma unroll
    for (int i = 0; i < 8; ++i) {                // Toeplitz T fill, packed u32 writes
        int q = tid + i * 256;                   // q in [0,2048): l = q>>5, jp = (q&31)*2
        int l = q >> 5, jp = (q & 31) * 2;
        int d0 = l - jp, d1 = d0 - 1;
        unsigned int pk = (unsigned int)f2bu(d0 >= 0 ? Tdh[d0] : 0.f)
                        | ((unsigned int)f2bu(d1 >= 0 ? Tdh[d1] : 0.f) << 16);
        *(unsigned int*)&A_s[l * 136 + jp] = pk;
    }
    f32x4 eacc[4][2];
#pragma unroll
    for (int mt = 0; mt < 4; ++mt)
#pragma unroll
        for (int nf = 0; nf < 2; ++nf) eacc[mt][nf] = (f32x4){0.f, 0.f, 0.f, 0.f};
#pragma unroll
    for (int ks = 0; ks < 2; ++ks)
#pragma unroll
        for (int mt = 0; mt < 4; ++mt)
#pragma unroll
            for (int nf = 0; nf < 2; ++nf)
                eacc[mt][nf] = __builtin_amdgcn_mfma_f32_16x16x32_bf16(va[ks][mt], ub[ks][nf], eacc[mt][nf], 0, 0, 0);
#pragma unroll
    for (int mt = 0; mt < 4; ++mt)               // E -> Eo_s [bc][comp], packed pairs
#pragma unroll
        for (int nf = 0; nf < 2; ++nf) {
            int bc = wv * 32 + nf * 16 + fr;
#pragma unroll
            for (int r = 0; r < 4; r += 2) {
                int comp = mt * 16 + quad * 4 + r;
                *(unsigned int*)&Eo_s[bc * 72 + comp] =
                    (unsigned int)f2bu(eacc[mt][nf][r]) | ((unsigned int)f2bu(eacc[mt][nf][r + 1]) << 16);
            }
        }
    __syncthreads();                             // Eo + A_s ready
    {                                            // in-place carry scan: thread = (b_local, n)
        int bl = tid >> 5, n = tid & 31;
        float2 a = PA[n * HDIM + h];
        float cr = 0.f, ci = 0.f;
#pragma unroll
        for (int c = 0; c < NCH; ++c) {
            int bc = bl * NCH + c;
            unsigned int* slot = (unsigned int*)&Eo_s[bc * 72 + 2 * n];
            unsigned int ev = *slot;
            *slot = (unsigned int)f2bu(cr) | ((unsigned int)f2bu(ci) << 16);
            float er = bu2f((unsigned short)(ev & 0xffff));
            float ei = bu2f((unsigned short)(ev >> 16));
            float nr = fmaf(a.x, cr, fmaf(-a.y, ci, er));
            ci = fmaf(a.x, ci, fmaf(a.y, cr, ei));
            cr = nr;
        }
    }
    __syncthreads();                             // carries in Eo_s
    // prefetch epilogue u-gathers (independent of MFMA results; L2-hot)
    uint2 uvp[4][2];
#pragma unroll
    for (int mt = 0; mt < 4; ++mt)
#pragma unroll
        for (int nf = 0; nf < 2; ++nf)
            uvp[mt][nf] = *(const uint2*)&Uh[(size_t)(wv * 32 + nf * 16 + fr) * 64 + mt * 16 + quad * 4];
    f32x4 acc[4][2];
#pragma unroll
    for (int mt = 0; mt < 4; ++mt)
#pragma unroll
        for (int nf = 0; nf < 2; ++nf) acc[mt][nf] = (f32x4){0.f, 0.f, 0.f, 0.f};

#define LDAB(AA, BB, KS) do { \
    _Pragma("unroll") \
    for (int mt = 0; mt < 4; ++mt) \
        AA[mt] = *(const bf16x8*)&A_s[(mt * 16 + fr) * 136 + (KS) * 32 + quad * 8]; \
    _Pragma("unroll") \
    for (int nf = 0; nf < 2; ++nf) \
        BB[nf] = ((KS) < 2) ? ub[(KS) & 1][nf] \
               : *(const bf16x8*)&Eo_s[(wv * 32 + nf * 16 + fr) * 72 + ((KS) & 1) * 32 + quad * 8]; \
    } while (0)
#define MFMAC(AA, BB) do { \
    _Pragma("unroll") \
    for (int mt = 0; mt < 4; ++mt) \
        _Pragma("unroll") \
        for (int nf = 0; nf < 2; ++nf) \
            acc[mt][nf] = __builtin_amdgcn_mfma_f32_16x16x32_bf16(AA[mt], BB[nf], acc[mt][nf], 0, 0, 0); \
    } while (0)

    {
        bf16x8 aA[4], bA[2], aB[4], bB[2];
        LDAB(aA, bA, 0);
        LDAB(aB, bB, 1);
        MFMAC(aA, bA);
        LDAB(aA, bA, 2);
        MFMAC(aB, bB);
        LDAB(aB, bB, 3);
        MFMAC(aA, bA);
        MFMAC(aB, bB);
    }
#undef LDAB
#undef MFMAC

    float Dv = Dw[h];
#pragma unroll
    for (int mt = 0; mt < 4; ++mt)
#pragma unroll
        for (int nf = 0; nf < 2; ++nf) {
            int bcl = wv * 32 + nf * 16 + fr;
            const bf16* up = (const bf16*)&uvp[mt][nf];
#pragma unroll
            for (int r = 0; r < 4; ++r) {
                int l = mt * 16 + quad * 4 + r;
                float u = __bfloat162float(up[r]);
                float v = fmaf(Dv, u, acc[mt][nf][r]);
                float z2 = 1.5957691216057308f * (v + 0.044715f * v * v * v);
                float sg = __builtin_amdgcn_rcpf(1.f + __expf(-z2));
                Eo_s[bcl * 72 + l] = __float2bfloat16(v * sg);
            }
        }
    __syncthreads();
#pragma unroll
    for (int i = 0; i < 4; ++i) {                // coalesced Yt store
        int q = tid + i * 256, row = q >> 3, c8 = q & 7;
        *(uint4*)&Yt[(size_t)h * M_ROWS + (size_t)(bc0 + row) * 64 + c8 * 8] =
            *(uint4*)&Eo_s[row * 72 + c8 * 8];
    }
}

// ---------------- FUSED output GEMM + GLU + residual + LayerNorm (+ decoder on last layer) ----
// r7: 512 threads / 8 waves, m-tile=64, grid 512. Each wave owns a 32-wide n-slice of BOTH GLU
// halves (acc = 4m x 2n x 2 = 64 VGPR). Wt read ONCE per block, amortized over 2x the output:
// total B-operand L1/L2 traffic halves (268 -> 134 MB/dispatch). launch_bounds(512,4) pins
// VGPR <= 128 -> 4 waves/SIMD (2 blocks/CU). LDS ~40.5 KB.
__global__ __launch_bounds__(512, 4) void k_gluln(const bf16* __restrict__ Yt,
                                                  const bf16* __restrict__ Wt,
                                                  const float* __restrict__ wb,
                                                  bf16* __restrict__ Hb,
                                                  const float* __restrict__ w,
                                                  const float* __restrict__ bbias,
                                                  bf16* __restrict__ Ut,
                                                  const float* __restrict__ dw,
                                                  const float* __restrict__ db,
                                                  float* __restrict__ outp, int mode) {
    __shared__ __align__(16) bf16 A_s[64 * 264];   // A tile [m][k]; then g [m][n]; mode1: dw overlay
    __shared__ float red[2][8][64];
    __shared__ float stat[2][64];
    __shared__ float w_s[256], b_s[256];
    __shared__ float db_s[16];
    int tid = threadIdx.x;
    int lane = tid & 63, wv = tid >> 6;            // wv in [0,8)
    int quad = lane >> 4, fr = lane & 15;
    int m0 = blockIdx.x * 64;
    int rr = tid & 63, qd = tid >> 6;              // LN coords: row 0..63, col-seg 0..7
    if (tid < 256) { w_s[tid] = w[tid]; b_s[tid] = bbias[tid]; }
    if (mode == 1 && tid < DOUT) db_s[tid] = db[tid];
    float bias1[2], bias2[2];
#pragma unroll
    for (int nt = 0; nt < 2; ++nt) {               // GLU biases -> regs (L2-hot)
        bias1[nt] = wb[wv * 32 + nt * 16 + fr];
        bias2[nt] = wb[HDIM + wv * 32 + nt * 16 + fr];
    }
    {                                              // stage A: Yt[k][m] -> A_s[m][k] (reg transpose)
        int mg = tid & 15, hg = tid >> 4;          // mg: 4-m group [0,16); hg: k-octet [0,32)
        uint2 rowv[8];
#pragma unroll
        for (int e = 0; e < 8; ++e)
            rowv[e] = *(const uint2*)&Yt[(size_t)(hg * 8 + e) * M_ROWS + m0 + mg * 4];
#pragma unroll
        for (int j = 0; j < 4; ++j) {
            unsigned int pk[4];
#pragma unroll
            for (int k2 = 0; k2 < 4; ++k2) {
                unsigned int lo = ((const unsigned short*)&rowv[2 * k2])[j];
                unsigned int hi = ((const unsigned short*)&rowv[2 * k2 + 1])[j];
                pk[k2] = lo | (hi << 16);
            }
            *(uint4*)&A_s[(mg * 4 + j) * 264 + hg * 8] = *(uint4*)pk;
        }
    }
    f32x4 acc1[4][2], acc2[4][2];                  // [m-frag][n-frag], both GLU halves
#pragma unroll
    for (int mt = 0; mt < 4; ++mt)
#pragma unroll
        for (int nt = 0; nt < 2; ++nt) {
            acc1[mt][nt] = (f32x4){0.f, 0.f, 0.f, 0.f};
            acc2[mt][nt] = (f32x4){0.f, 0.f, 0.f, 0.f};
        }
    __syncthreads();

    // B frags: wave wv -> n-blocks nb = wv*2+nt (half1), 16+wv*2+nt (half2)
#define LOAD_B(d1, d2, KS) do { \
    _Pragma("unroll") \
    for (int nt = 0; nt < 2; ++nt) { \
        d1[nt] = *(const bf16x8*)&Wt[((size_t)((wv * 2 + nt) * 8 + (KS)) * 64 + lane) * 8]; \
        d2[nt] = *(const bf16x8*)&Wt[((size_t)((16 + wv * 2 + nt) * 8 + (KS)) * 64 + lane) * 8]; \
    } } while (0)

#define DO_MFMA(bb1, bb2, KS) do { \
    bf16x8 afr[4]; \
    _Pragma("unroll") \
    for (int mt = 0; mt < 4; ++mt) \
        afr[mt] = *(const bf16x8*)&A_s[(mt * 16 + fr) * 264 + (KS) * 32 + quad * 8]; \
    _Pragma("unroll") \
    for (int mt = 0; mt < 4; ++mt) \
        _Pragma("unroll") \
        for (int nt = 0; nt < 2; ++nt) { \
            acc1[mt][nt] = __builtin_amdgcn_mfma_f32_16x16x32_bf16(afr[mt], bb1[nt], acc1[mt][nt], 0, 0, 0); \
            acc2[mt][nt] = __builtin_amdgcn_mfma_f32_16x16x32_bf16(afr[mt], bb2[nt], acc2[mt][nt], 0, 0, 0); \
        } } while (0)

    {
        bf16x8 p1[2], p2[2], q1[2], q2[2];
        LOAD_B(p1, p2, 0);
#pragma unroll
        for (int kp = 0; kp < 4; ++kp) {
            LOAD_B(q1, q2, 2 * kp + 1);
            DO_MFMA(p1, p2, 2 * kp);
            if (kp < 3) LOAD_B(p1, p2, 2 * kp + 2);
            DO_MFMA(q1, q2, 2 * kp + 1);
        }
    }
#undef LOAD_B
#undef DO_MFMA

    __syncthreads();                               // A_s dead as A-tile; reuse for g [m][n]
#pragma unroll
    for (int mt = 0; mt < 4; ++mt)
#pragma unroll
        for (int nt = 0; nt < 2; ++nt) {
            int n = wv * 32 + nt * 16 + fr;
#pragma unroll
            for (int r = 0; r < 4; ++r) {
                int m = mt * 16 + quad * 4 + r;
                float z1 = acc1[mt][nt][r] + bias1[nt];
                float z2 = acc2[mt][nt][r] + bias2[nt];
                float sg = __builtin_amdgcn_rcpf(1.0f + __expf(-z2));
                A_s[m * 264 + n] = __float2bfloat16(z1 * sg);
            }
        }
    __syncthreads();                               // g complete
    const bf16* Hr = Hb + (size_t)(m0 + rr) * HDIM + qd * 32;
    float rv[32];
    float sum = 0.f, sq = 0.f;
#pragma unroll
    for (int i4 = 0; i4 < 4; ++i4) {
        uint4 gv = *(uint4*)&A_s[rr * 264 + qd * 32 + i4 * 8];
        uint4 hv4 = *(const uint4*)&Hr[i4 * 8];
        const bf16* gp = (const bf16*)&gv;
        const bf16* hp = (const bf16*)&hv4;
#pragma unroll
        for (int e = 0; e < 8; ++e) {
            float v = __bfloat162float(gp[e]) + __bfloat162float(hp[e]);
            rv[i4 * 8 + e] = v; sum += v; sq += v * v;
        }
    }
    red[0][qd][rr] = sum; red[1][qd][rr] = sq;
    __syncthreads();
    if (tid < 64) {
        float s = 0.f, s2 = 0.f;
#pragma unroll
        for (int q = 0; q < 8; ++q) { s += red[0][q][tid]; s2 += red[1][q][tid]; }
        float mean = s * (1.f / HDIM);
        float var = s2 * (1.f / HDIM) - mean * mean;
        stat[0][tid] = mean; stat[1][tid] = rsqrtf(var + 1e-5f);
    }
    __syncthreads();
    float mean = stat[0][rr], rstd = stat[1][rr];
#pragma unroll
    for (int j = 0; j < 32; ++j)
        rv[j] = (rv[j] - mean) * rstd * w_s[qd * 32 + j] + b_s[qd * 32 + j];
    if (mode == 0) {
        // packed bf16 H write (new residual = LN out)
        bf16* Hw = Hb + (size_t)(m0 + rr) * HDIM + qd * 32;
#pragma unroll
        for (int j = 0; j < 32; j += 8) {
            unsigned int pk[4];
#pragma unroll
            for (int e = 0; e < 4; ++e)
                pk[e] = (unsigned int)f2bu(rv[j + 2 * e]) | ((unsigned int)f2bu(rv[j + 2 * e + 1]) << 16);
            *(uint4*)&Hw[j] = *(uint4*)pk;
        }
        // direct Ut store: [h][m], lanes rr 0..63 contiguous -> full 128B line per wave store
        bf16* Up = Ut + (size_t)(qd * 32) * M_ROWS + m0 + rr;
#pragma unroll
        for (int j = 0; j < 32; ++j)
            Up[(size_t)j * M_ROWS] = __float2bfloat16(rv[j]);
    } else {
        // decoder: stage dec_w over dead A_s (g fully consumed into rv, fenced by red barrier)
        float* dwf = (float*)A_s;                  // 2560 floats = 10240 B
        for (int e = tid; e < HDIM * DOUT; e += 512) dwf[e] = dw[e];
        __syncthreads();
        float part[DOUT];
#pragma unroll
        for (int o = 0; o < DOUT; ++o) part[o] = 0.f;
#pragma unroll
        for (int j = 0; j < 32; ++j) {
            float tv = rv[j];
            const float* dr = &dwf[(qd * 32 + j) * DOUT];
#pragma unroll
            for (int o = 0; o < DOUT; ++o) part[o] = fmaf(tv, dr[o], part[o]);
        }
        // reduce across the 8 qd-groups, 2 outputs per pass via red
#pragma unroll
        for (int oc = 0; oc < 5; ++oc) {
            red[0][qd][rr] = part[2 * oc];
            red[1][qd][rr] = part[2 * oc + 1];
            __syncthreads();
            if (tid < 128) {
                int rl = tid & 63, ph = tid >> 6;
                float s = 0.f;
#pragma unroll
                for (int q = 0; q < 8; ++q) s += red[ph][q][rl];
                int o = 2 * oc + ph;
                outp[(size_t)(m0 + rl) * DOUT + o] = s + db_s[o];
            }
            __syncthreads();
        }
    }
}

extern "C" void kernel_launch(void* const* d_in, const int* in_sizes, int n_in,
                              void* d_out, int out_size, void* d_ws, size_t ws_size,
                              hipStream_t stream) {
    const float* x        = (const float*)d_in[0];
    const float* enc_w    = (const float*)d_in[1];
    const float* enc_b    = (const float*)d_in[2];
    const float* log_dt   = (const float*)d_in[3];
    const float* A_re_log = (const float*)d_in[4];
    const float* A_im     = (const float*)d_in[5];
    const float* B_re     = (const float*)d_in[6];
    const float* B_im     = (const float*)d_in[7];
    const float* C_re     = (const float*)d_in[8];
    const float* C_im     = (const float*)d_in[9];
    const float* Dp       = (const float*)d_in[10];
    const float* ln_w     = (const float*)d_in[11];
    const float* ln_b     = (const float*)d_in[12];
    const float* out_w    = (const float*)d_in[13];
    const float* out_b    = (const float*)d_in[14];
    const float* dec_w    = (const float*)d_in[15];
    const float* dec_b    = (const float*)d_in[16];
    float* outp = (float*)d_out;

    float* w = (float*)d_ws;
    const size_t PWE = (size_t)NLAYERS * NSTATE * HDIM;   // 32768
    const size_t MH  = (size_t)M_ROWS * HDIM;             // 8388608
    const size_t VME = (size_t)NLAYERS * HDIM * 64 * 64;  // 4M elems/matrix
    float2* PA64 = (float2*)(w + 4 * PWE);                // 256 KB
    float*  Td   = w + 6 * PWE;                           // 270 KB
    bf16*   Hbuf = (bf16*)(Td + (size_t)NLAYERS * HDIM * 66);  // 16.7 MB bf16
    bf16*   Ut   = Hbuf + MH;                             // 16.7 MB
    bf16*   Yt   = Ut + MH;                               // 16.7 MB
    bf16*   Wt   = Yt + MH;                               // 1 MB (G buffer eliminated)
    bf16*   Wet  = Wt + (size_t)NLAYERS * 512 * HDIM;     // 64 KB
    bf16*   Vg   = Wet + (size_t)HDIM * DIN;              // 8 MB (all layers)
    bf16*   Mg   = Vg + VME;                              // 8 MB (all layers)

    {
        int total = VMB_ + TDB_ + PAB_ + WCB_ + HDIM * DIN / 256;
        k_setup<<<total, 256, 0, stream>>>(log_dt, A_re_log, A_im, B_re, B_im, C_re, C_im,
                                           out_w, enc_w, Td, Vg, Mg, PA64, Wt, Wet);
    }

    dim3 ge(M_ROWS / 128, HDIM / 64);
    k_enc2<<<ge, 256, 0, stream>>>(x, Wet, enc_b, Hbuf, Ut);

    dim3 gconv(HDIM, NBC / 128);
    for (int layer = 0; layer < NLAYERS; ++layer) {
        const float2* pal = PA64 + (size_t)layer * NSTATE * HDIM;
        const float*  tdl = Td + (size_t)layer * HDIM * 66;
        const bf16*   vgl = Vg + (size_t)layer * HDIM * 64 * 64;
        const bf16*   mgl = Mg + (size_t)layer * HDIM * 64 * 64;
        k_conv<<<gconv, 256, 0, stream>>>(Ut, vgl, mgl, tdl, pal, Dp + layer * HDIM, Yt);
        k_gluln<<<M_ROWS / 64, 512, 0, stream>>>(Yt, Wt + (size_t)layer * 512 * HDIM,
                                                 out_b + layer * 2 * HDIM, Hbuf,
                                                 ln_w + layer * HDIM, ln_b + layer * HDIM,
                                                 Ut, dec_w, dec_b, outp,
                                                 layer == NLAYERS - 1 ? 1 : 0);
    }
}

// Round 8
// 296.331 us; speedup vs baseline: 1.1879x; 1.0022x over previous
//
#include <hip/hip_runtime.h>
#include <hip/hip_bf16.h>
#include <math.h>

#define B_SZ    32
#define LSEQ    1024
#define DIN     128
#define HDIM    256
#define NLAYERS 4
#define NSTATE  32
#define DOUT    10
#define M_ROWS  (B_SZ*LSEQ)   // 32768
#define CH      64            // scan chunk length
#define NCH     (LSEQ/CH)     // 16 chunks
#define NBC     (B_SZ*NCH)    // 512 chunk-columns

typedef __hip_bfloat16 bf16;
typedef __attribute__((ext_vector_type(8))) short bf16x8;
typedef __attribute__((ext_vector_type(4))) float f32x4;

__device__ __forceinline__ unsigned short f2bu(float x) {
    bf16 b = __float2bfloat16(x);
    return *(unsigned short*)&b;
}
__device__ __forceinline__ float bu2f(unsigned short u) {
    bf16 b = *(bf16*)&u;
    return __bfloat162float(b);
}

// inline S4D discretization: returns (dtAre, dtAim, Wre, Wim)
__device__ __forceinline__ float4 s4param(const float* __restrict__ log_dt,
                                          const float* __restrict__ A_re_log,
                                          const float* __restrict__ A_im,
                                          const float* __restrict__ B_re,
                                          const float* __restrict__ B_im,
                                          const float* __restrict__ C_re,
                                          const float* __restrict__ C_im,
                                          int layer, int h, int n) {
    int hn = layer * HDIM + h;
    int idx = hn * NSTATE + n;
    float dt   = expf(log_dt[hn]);
    float Are  = -expf(A_re_log[idx]);
    float Aim  = A_im[idx];
    float dtAre = dt * Are, dtAim = dt * Aim;
    float ea   = expf(dtAre);
    float dAre = ea * cosf(dtAim), dAim = ea * sinf(dtAim);
    float nre = dAre - 1.0f, nim = dAim;
    float inv = 1.0f / (Are * Are + Aim * Aim);
    float tre = (nre * Are + nim * Aim) * inv;
    float tim = (nim * Are - nre * Aim) * inv;
    float Brv = B_re[idx], Biv = B_im[idx];
    float dBre = Brv * tre - Biv * tim;
    float dBim = Brv * tim + Biv * tre;
    float Crv = C_re[idx], Civ = C_im[idx];
    float Wre = Crv * dBre - Civ * dBim;
    float Wim = Crv * dBim + Civ * dBre;
    return make_float4(dtAre, dtAim, Wre, Wim);
}

// ---------------- ONE setup kernel: V/M, Td, PA64, weight transposes ----------------
// r3: Vg and Wt stored FRAGMENT-MAJOR so consumer wave-loads are base+lane*16B coalesced.
#define VMB_ (NLAYERS*HDIM*64*32/256)    // 8192
#define TDB_ ((NLAYERS*HDIM*66+255)/256) // 264
#define PAB_ (NLAYERS*NSTATE*HDIM/256)   // 128
#define WCB_ (NLAYERS*512*256/256)       // 2048
__global__ void k_setup(const float* __restrict__ log_dt, const float* __restrict__ A_re_log,
                        const float* __restrict__ A_im, const float* __restrict__ B_re,
                        const float* __restrict__ B_im, const float* __restrict__ C_re,
                        const float* __restrict__ C_im, const float* __restrict__ out_w,
                        const float* __restrict__ enc_w, float* __restrict__ Td,
                        bf16* __restrict__ Vg, bf16* __restrict__ Mg,
                        float2* __restrict__ PA64, bf16* __restrict__ Wt,
                        bf16* __restrict__ Wet) {
    const float inv2pi = 0.15915494309189535f;
    const float twopi  = 6.283185307179586f;
    int bx = blockIdx.x;
    if (bx < VMB_) {                                 // V/M pair-elements
        int gid = bx * 256 + threadIdx.x;
        int jp = (gid & 31) * 2;
        int row = gid >> 5;                          // ((layer*256+h)*64)+comp
        int comp = row & 63, h = (row >> 6) & 255, layer = row >> 14;
        int n = comp >> 1, isIm = comp & 1;
        float4 q = s4param(log_dt, A_re_log, A_im, B_re, B_im, C_re, C_im, layer, h, n);
        unsigned int vpk = 0, mpk = 0;
#pragma unroll
        for (int e = 0; e < 2; ++e) {
            int j = jp + e;
            float dv = (float)(63 - j);
            float magv = __expf(dv * q.x);
            float pr = dv * q.y * inv2pi;
            float th = (pr - floorf(pr)) * twopi;
            float c = __cosf(th), s = __sinf(th);
            float vre = magv * (q.z * c - q.w * s);
            float vim = magv * (q.z * s + q.w * c);
            vpk |= (unsigned int)f2bu(isIm ? vim : vre) << (16 * e);
            float dm = (float)(j + 1);
            float magm = __expf(dm * q.x);
            float pr2 = dm * q.y * inv2pi;
            float th2 = (pr2 - floorf(pr2)) * twopi;
            float mv = isIm ? (-2.f * magm * __sinf(th2)) : (2.f * magm * __cosf(th2));
            mpk |= (unsigned int)f2bu(mv) << (16 * e);
        }
        // V fragment-major within (layer,h) 64x64 block
        {
            int mtv = comp >> 4, frv = comp & 15;
            int ksv = jp >> 5, qdv = (jp >> 3) & 3, ev = jp & 7;
            size_t voff = (size_t)(layer * 256 + h) * 4096
                        + ((size_t)((mtv * 2 + ksv) * 64) + qdv * 16 + frv) * 8 + ev;
            ((unsigned int*)Vg)[voff >> 1] = vpk;    // jp even -> voff even
        }
        ((unsigned int*)Mg)[(size_t)row * 32 + (jp >> 1)] = mpk;   // M row-major (LDS-staged)
    } else if (bx < VMB_ + TDB_) {                   // Td
        int gid = (bx - VMB_) * 256 + threadIdx.x;
        int d = gid % 66;
        int lh = gid / 66;
        if (lh < NLAYERS * HDIM && d < 65) {
            int layer = lh >> 8, h = lh & 255;
            float fd = (float)d;
            float acc = 0.f;
            for (int n = 0; n < NSTATE; ++n) {
                float4 q = s4param(log_dt, A_re_log, A_im, B_re, B_im, C_re, C_im, layer, h, n);
                float mag = __expf(fd * q.x);
                float pr = fd * q.y * inv2pi;
                float th = (pr - floorf(pr)) * twopi;
                acc += mag * (q.z * __cosf(th) - q.w * __sinf(th));
            }
            Td[(size_t)lh * 66 + d] = 2.f * acc;
        }
    } else if (bx < VMB_ + TDB_ + PAB_) {            // PA64 = dA^64 per (layer,n,h)
        int idx = (bx - VMB_ - TDB_) * 256 + threadIdx.x;
        int h = idx & 255, n = (idx >> 8) & 31, layer = idx >> 13;
        float4 q = s4param(log_dt, A_re_log, A_im, B_re, B_im, C_re, C_im, layer, h, n);
        float e64 = expf(64.0f * q.x);
        float ph  = 64.0f * q.y;
        PA64[idx] = make_float2(e64 * cosf(ph), e64 * sinf(ph));
    } else if (bx < VMB_ + TDB_ + PAB_ + WCB_) {     // Wt fragment-major
        int idx = (bx - VMB_ - TDB_ - PAB_) * 256 + threadIdx.x;
        int k = idx & 255;
        int n = (idx >> 8) & 511;
        int layer = idx >> 17;
        // [nb=n>>4][ks=k>>5][quad=(k>>3)&3][fr=n&15][e=k&7]
        size_t off = (size_t)layer * (512 * 256)
                   + ((size_t)((n >> 4) * 8 + (k >> 5)) * 64 + (((k >> 3) & 3) * 16 + (n & 15))) * 8
                   + (k & 7);
        Wt[off] = __float2bfloat16(out_w[((size_t)(layer * 256 + k)) * 512 + n]);
    } else {                                         // Wet transpose
        int idx = (bx - VMB_ - TDB_ - PAB_ - WCB_) * 256 + threadIdx.x;
        int k = idx & 127, n = idx >> 7;
        Wet[idx] = __float2bfloat16(enc_w[(size_t)k * HDIM + n]);
    }
}

// ---------------- encoder GEMM (bf16 MFMA): H(bf16) = X@We + b, + transposed Ut ----------------
__global__ __launch_bounds__(256) void k_enc2(const float* __restrict__ X, const bf16* __restrict__ Wet,
                                              const float* __restrict__ bias, bf16* __restrict__ H,
                                              bf16* __restrict__ Ut) {
    __shared__ bf16 A_s[128 * 136];
    __shared__ bf16 B_s[64 * 136];
    int tid = threadIdx.x;
    int lane = tid & 63, wv = tid >> 6, quad = lane >> 4, fr = lane & 15;
    int m0 = blockIdx.x * 128, n0 = blockIdx.y * 64;
#pragma unroll
    for (int i = 0; i < 16; ++i) {               // stage X fp32 -> bf16 [m][k]
        int q = tid + i * 256, row = q >> 5, seg = q & 31;
        float4 v = *(const float4*)&X[(size_t)(m0 + row) * DIN + seg * 4];
        bf16* dst = &A_s[row * 136 + seg * 4];
        dst[0] = __float2bfloat16(v.x); dst[1] = __float2bfloat16(v.y);
        dst[2] = __float2bfloat16(v.z); dst[3] = __float2bfloat16(v.w);
    }
#pragma unroll
    for (int i = 0; i < 4; ++i) {                // stage Wet [n][k]
        int q = tid + i * 256, row = q >> 4, seg = q & 15;
        *(uint4*)&B_s[row * 136 + seg * 8] = *(const uint4*)&Wet[(size_t)(n0 + row) * DIN + seg * 8];
    }
    __syncthreads();
    f32x4 acc[2][4];
#pragma unroll
    for (int mt = 0; mt < 2; ++mt)
#pragma unroll
        for (int nt = 0; nt < 4; ++nt) acc[mt][nt] = (f32x4){0.f, 0.f, 0.f, 0.f};
#pragma unroll
    for (int ks = 0; ks < 4; ++ks) {
        bf16x8 a[2], b[4];
#pragma unroll
        for (int mt = 0; mt < 2; ++mt)
            a[mt] = *(const bf16x8*)&A_s[(wv * 32 + mt * 16 + fr) * 136 + ks * 32 + quad * 8];
#pragma unroll
        for (int nt = 0; nt < 4; ++nt)
            b[nt] = *(const bf16x8*)&B_s[(nt * 16 + fr) * 136 + ks * 32 + quad * 8];
#pragma unroll
        for (int mt = 0; mt < 2; ++mt)
#pragma unroll
            for (int nt = 0; nt < 4; ++nt)
                acc[mt][nt] = __builtin_amdgcn_mfma_f32_16x16x32_bf16(a[mt], b[nt], acc[mt][nt], 0, 0, 0);
    }
    __syncthreads();                             // B_s reuse as transpose bounce
#pragma unroll
    for (int mt = 0; mt < 2; ++mt)
#pragma unroll
        for (int nt = 0; nt < 4; ++nt) {
            int n = n0 + nt * 16 + fr;
            float bv = bias[n];
#pragma unroll
            for (int r = 0; r < 4; ++r) {
                int m = m0 + wv * 32 + mt * 16 + quad * 4 + r;
                float hv = acc[mt][nt][r] + bv;
                bf16 hb = __float2bfloat16(hv);
                H[(size_t)m * HDIM + n] = hb;
                B_s[(nt * 16 + fr) * 136 + (wv * 32 + mt * 16 + quad * 4 + r)] = hb;
            }
        }
    __syncthreads();
#pragma unroll
    for (int i = 0; i < 4; ++i) {                // coalesced Ut store [h][m]
        int q = tid + i * 256, row = q >> 4, seg = q & 15;
        *(uint4*)&Ut[(size_t)(n0 + row) * M_ROWS + m0 + seg * 8] = *(uint4*)&B_s[row * 136 + seg * 8];
    }
}

// ---------------- fused conv ----------------
// r8: structural pass. (1) carry scan rewritten read-all -> register fma chain -> write-all
// (was a serial LDS RMW chain, ~2.5K cy -> ~0.5K cy). (2) barriers 4 -> 2: the E-pack -> scan ->
// 2nd-loop Eo_s dataflow is WAVE-LOCAL (wave wv packs rows [32wv,32wv+32); scan bl=tid>>5 reads
// exactly those; 2nd-loop carry reads are own-row) so wave-synchronous program order suffices.
// Only A_s (cross-wave staging) and the Yt store phase need __syncthreads. (3) PA/Dw hoisted.
__global__ __launch_bounds__(256) void k_conv(const bf16* __restrict__ Ut,
                                              const bf16* __restrict__ Vg,
                                              const bf16* __restrict__ Mg,
                                              const float* __restrict__ Tdl,
                                              const float2* __restrict__ PA,
                                              const float* __restrict__ Dw,
                                              bf16* __restrict__ Yt) {
    __shared__ bf16 A_s[64 * 136];               // [l][k2], k2<64: T, k2>=64: M
    __shared__ bf16 Eo_s[128 * 72];              // [bc][comp]: E, then carries, then o_s
    int h = blockIdx.x, bc0 = blockIdx.y * 128;
    int tid = threadIdx.x;
    int lane = tid & 63, wv = tid >> 6, quad = lane >> 4, fr = lane & 15;
    const float* Tdh = Tdl + (size_t)h * 66;
    const bf16* Uh = Ut + (size_t)h * M_ROWS + (size_t)bc0 * 64;
    // prologue: ALL global operands issued up front (batched, independent)
    bf16x8 va[2][4], ub[2][2];
#pragma unroll
    for (int ks = 0; ks < 2; ++ks) {
#pragma unroll
        for (int mt = 0; mt < 4; ++mt)           // fragment-major Vg: coalesced
            va[ks][mt] = *(const bf16x8*)&Vg[(size_t)h * 4096 + ((size_t)((mt * 2 + ks) * 64) + lane) * 8];
#pragma unroll
        for (int nf = 0; nf < 2; ++nf)
            ub[ks][nf] = *(const bf16x8*)&Uh[(size_t)(wv * 32 + nf * 16 + fr) * 64 + ks * 32 + quad * 8];
    }
    float2 pa = PA[(tid & 31) * HDIM + h];       // scan coefficient (thread = (bl, n))
    float Dv = Dw[h];
#pragma unroll
    for (int i = 0; i < 2; ++i) {                // stage M transposed into A_s cols 64..127
        int q = tid + i * 256, comp = q >> 3, seg = q & 7;
        uint4 v = *(const uint4*)&Mg[((size_t)h * 64 + comp) * 64 + seg * 8];
        const bf16* pv = (const bf16*)&v;
#pragma unroll
        for (int e = 0; e < 8; ++e) A_s[(seg * 8 + e) * 136 + 64 + comp] = pv[e];
    }
#pragma unroll
    for (int i = 0; i < 8; ++i) {                // Toeplitz T fill, packed u32 writes
        int q = tid + i * 256;                   // q in [0,2048): l = q>>5, jp = (q&31)*2
        int l = q >> 5, jp = (q & 31) * 2;
        int d0 = l - jp, d1 = d0 - 1;
        unsigned int pk = (unsigned int)f2bu(d0 >= 0 ? Tdh[d0] : 0.f)
                        | ((unsigned int)f2bu(d1 >= 0 ? Tdh[d1] : 0.f) << 16);
        *(unsigned int*)&A_s[l * 136 + jp] = pk;
    }
    f32x4 eacc[4][2];
#pragma unroll
    for (int mt = 0; mt < 4; ++mt)
#pragma unroll
        for (int nf = 0; nf < 2; ++nf) eacc[mt][nf] = (f32x4){0.f, 0.f, 0.f, 0.f};
#pragma unroll
    for (int ks = 0; ks < 2; ++ks)
#pragma unroll
        for (int mt = 0; mt < 4; ++mt)
#pragma unroll
            for (int nf = 0; nf < 2; ++nf)
                eacc[mt][nf] = __builtin_amdgcn_mfma_f32_16x16x32_bf16(va[ks][mt], ub[ks][nf], eacc[mt][nf], 0, 0, 0);
#pragma unroll
    for (int mt = 0; mt < 4; ++mt)               // E -> Eo_s [bc][comp]; wave-local rows
#pragma unroll
        for (int nf = 0; nf < 2; ++nf) {
            int bc = wv * 32 + nf * 16 + fr;
#pragma unroll
            for (int r = 0; r < 4; r += 2) {
                int comp = mt * 16 + quad * 4 + r;
                *(unsigned int*)&Eo_s[bc * 72 + comp] =
                    (unsigned int)f2bu(eacc[mt][nf][r]) | ((unsigned int)f2bu(eacc[mt][nf][r + 1]) << 16);
            }
        }
    {   // wave-local carry scan (no barrier: reads/writes only this wave's rows, program-ordered)
        int bl = tid >> 5, n = tid & 31;         // bl in {2wv, 2wv+1} -> rows [32wv, 32wv+32)
        unsigned int ev[NCH];
#pragma unroll
        for (int c = 0; c < NCH; ++c)            // batched independent LDS reads (pipelined)
            ev[c] = *(unsigned int*)&Eo_s[(bl * NCH + c) * 72 + 2 * n];
        float cr = 0.f, ci = 0.f;
#pragma unroll
        for (int c = 0; c < NCH; ++c) {          // pure-register recurrence
            unsigned int wvp = (unsigned int)f2bu(cr) | ((unsigned int)f2bu(ci) << 16);
            float er = bu2f((unsigned short)(ev[c] & 0xffff));
            float ei = bu2f((unsigned short)(ev[c] >> 16));
            float nr = fmaf(pa.x, cr, fmaf(-pa.y, ci, er));
            ci = fmaf(pa.x, ci, fmaf(pa.y, cr, ei));
            cr = nr;
            ev[c] = wvp;
        }
#pragma unroll
        for (int c = 0; c < NCH; ++c)            // batched independent LDS writes
            *(unsigned int*)&Eo_s[(bl * NCH + c) * 72 + 2 * n] = ev[c];
    }
    __syncthreads();                             // A_s (cross-wave) + carries ready
    // prefetch epilogue u-gathers (independent of MFMA results; L2-hot)
    uint2 uvp[4][2];
#pragma unroll
    for (int mt = 0; mt < 4; ++mt)
#pragma unroll
        for (int nf = 0; nf < 2; ++nf)
            uvp[mt][nf] = *(const uint2*)&Uh[(size_t)(wv * 32 + nf * 16 + fr) * 64 + mt * 16 + quad * 4];
    f32x4 acc[4][2];
#pragma unroll
    for (int mt = 0; mt < 4; ++mt)
#pragma unroll
        for (int nf = 0; nf < 2; ++nf) acc[mt][nf] = (f32x4){0.f, 0.f, 0.f, 0.f};

#define LDAB(AA, BB, KS) do { \
    _Pragma("unroll") \
    for (int mt = 0; mt < 4; ++mt) \
        AA[mt] = *(const bf16x8*)&A_s[(mt * 16 + fr) * 136 + (KS) * 32 + quad * 8]; \
    _Pragma("unroll") \
    for (int nf = 0; nf < 2; ++nf) \
        BB[nf] = ((KS) < 2) ? ub[(KS) & 1][nf] \
               : *(const bf16x8*)&Eo_s[(wv * 32 + nf * 16 + fr) * 72 + ((KS) & 1) * 32 + quad * 8]; \
    } while (0)
#define MFMAC(AA, BB) do { \
    _Pragma("unroll") \
    for (int mt = 0; mt < 4; ++mt) \
        _Pragma("unroll") \
        for (int nf = 0; nf < 2; ++nf) \
            acc[mt][nf] = __builtin_amdgcn_mfma_f32_16x16x32_bf16(AA[mt], BB[nf], acc[mt][nf], 0, 0, 0); \
    } while (0)

    {
        bf16x8 aA[4], bA[2], aB[4], bB[2];
        LDAB(aA, bA, 0);
        LDAB(aB, bB, 1);
        MFMAC(aA, bA);
        LDAB(aA, bA, 2);
        MFMAC(aB, bB);
        LDAB(aB, bB, 3);
        MFMAC(aA, bA);
        MFMAC(aB, bB);
    }
#undef LDAB
#undef MFMAC

#pragma unroll
    for (int mt = 0; mt < 4; ++mt)
#pragma unroll
        for (int nf = 0; nf < 2; ++nf) {
            int bcl = wv * 32 + nf * 16 + fr;
            const bf16* up = (const bf16*)&uvp[mt][nf];
#pragma unroll
            for (int r = 0; r < 4; ++r) {
                int l = mt * 16 + quad * 4 + r;
                float u = __bfloat162float(up[r]);
                float v = fmaf(Dv, u, acc[mt][nf][r]);
                float z2 = 1.5957691216057308f * (v + 0.044715f * v * v * v);
                float sg = __builtin_amdgcn_rcpf(1.f + __expf(-z2));
                Eo_s[bcl * 72 + l] = __float2bfloat16(v * sg);   // own rows only
            }
        }
    __syncthreads();                             // cross-wave for transposed store
#pragma unroll
    for (int i = 0; i < 4; ++i) {                // coalesced Yt store
        int q = tid + i * 256, row = q >> 3, c8 = q & 7;
        *(uint4*)&Yt[(size_t)h * M_ROWS + (size_t)(bc0 + row) * 64 + c8 * 8] =
            *(uint4*)&Eo_s[row * 72 + c8 * 8];
    }
}

// ---------------- FUSED output GEMM + GLU + residual + LayerNorm (+ decoder on last layer) ----
// r7 (unchanged): 512 threads / 8 waves, m-tile=64, grid 512.
__global__ __launch_bounds__(512, 4) void k_gluln(const bf16* __restrict__ Yt,
                                                  const bf16* __restrict__ Wt,
                                                  const float* __restrict__ wb,
                                                  bf16* __restrict__ Hb,
                                                  const float* __restrict__ w,
                                                  const float* __restrict__ bbias,
                                                  bf16* __restrict__ Ut,
                                                  const float* __restrict__ dw,
                                                  const float* __restrict__ db,
                                                  float* __restrict__ outp, int mode) {
    __shared__ __align__(16) bf16 A_s[64 * 264];   // A tile [m][k]; then g [m][n]; mode1: dw overlay
    __shared__ float red[2][8][64];
    __shared__ float stat[2][64];
    __shared__ float w_s[256], b_s[256];
    __shared__ float db_s[16];
    int tid = threadIdx.x;
    int lane = tid & 63, wv = tid >> 6;            // wv in [0,8)
    int quad = lane >> 4, fr = lane & 15;
    int m0 = blockIdx.x * 64;
    int rr = tid & 63, qd = tid >> 6;              // LN coords: row 0..63, col-seg 0..7
    if (tid < 256) { w_s[tid] = w[tid]; b_s[tid] = bbias[tid]; }
    if (mode == 1 && tid < DOUT) db_s[tid] = db[tid];
    float bias1[2], bias2[2];
#pragma unroll
    for (int nt = 0; nt < 2; ++nt) {               // GLU biases -> regs (L2-hot)
        bias1[nt] = wb[wv * 32 + nt * 16 + fr];
        bias2[nt] = wb[HDIM + wv * 32 + nt * 16 + fr];
    }
    {                                              // stage A: Yt[k][m] -> A_s[m][k] (reg transpose)
        int mg = tid & 15, hg = tid >> 4;          // mg: 4-m group [0,16); hg: k-octet [0,32)
        uint2 rowv[8];
#pragma unroll
        for (int e = 0; e < 8; ++e)
            rowv[e] = *(const uint2*)&Yt[(size_t)(hg * 8 + e) * M_ROWS + m0 + mg * 4];
#pragma unroll
        for (int j = 0; j < 4; ++j) {
            unsigned int pk[4];
#pragma unroll
            for (int k2 = 0; k2 < 4; ++k2) {
                unsigned int lo = ((const unsigned short*)&rowv[2 * k2])[j];
                unsigned int hi = ((const unsigned short*)&rowv[2 * k2 + 1])[j];
                pk[k2] = lo | (hi << 16);
            }
            *(uint4*)&A_s[(mg * 4 + j) * 264 + hg * 8] = *(uint4*)pk;
        }
    }
    f32x4 acc1[4][2], acc2[4][2];                  // [m-frag][n-frag], both GLU halves
#pragma unroll
    for (int mt = 0; mt < 4; ++mt)
#pragma unroll
        for (int nt = 0; nt < 2; ++nt) {
            acc1[mt][nt] = (f32x4){0.f, 0.f, 0.f, 0.f};
            acc2[mt][nt] = (f32x4){0.f, 0.f, 0.f, 0.f};
        }
    __syncthreads();

    // B frags: wave wv -> n-blocks nb = wv*2+nt (half1), 16+wv*2+nt (half2)
#define LOAD_B(d1, d2, KS) do { \
    _Pragma("unroll") \
    for (int nt = 0; nt < 2; ++nt) { \
        d1[nt] = *(const bf16x8*)&Wt[((size_t)((wv * 2 + nt) * 8 + (KS)) * 64 + lane) * 8]; \
        d2[nt] = *(const bf16x8*)&Wt[((size_t)((16 + wv * 2 + nt) * 8 + (KS)) * 64 + lane) * 8]; \
    } } while (0)

#define DO_MFMA(bb1, bb2, KS) do { \
    bf16x8 afr[4]; \
    _Pragma("unroll") \
    for (int mt = 0; mt < 4; ++mt) \
        afr[mt] = *(const bf16x8*)&A_s[(mt * 16 + fr) * 264 + (KS) * 32 + quad * 8]; \
    _Pragma("unroll") \
    for (int mt = 0; mt < 4; ++mt) \
        _Pragma("unroll") \
        for (int nt = 0; nt < 2; ++nt) { \
            acc1[mt][nt] = __builtin_amdgcn_mfma_f32_16x16x32_bf16(afr[mt], bb1[nt], acc1[mt][nt], 0, 0, 0); \
            acc2[mt][nt] = __builtin_amdgcn_mfma_f32_16x16x32_bf16(afr[mt], bb2[nt], acc2[mt][nt], 0, 0, 0); \
        } } while (0)

    {
        bf16x8 p1[2], p2[2], q1[2], q2[2];
        LOAD_B(p1, p2, 0);
#pragma unroll
        for (int kp = 0; kp < 4; ++kp) {
            LOAD_B(q1, q2, 2 * kp + 1);
            DO_MFMA(p1, p2, 2 * kp);
            if (kp < 3) LOAD_B(p1, p2, 2 * kp + 2);
            DO_MFMA(q1, q2, 2 * kp + 1);
        }
    }
#undef LOAD_B
#undef DO_MFMA

    __syncthreads();                               // A_s dead as A-tile; reuse for g [m][n]
#pragma unroll
    for (int mt = 0; mt < 4; ++mt)
#pragma unroll
        for (int nt = 0; nt < 2; ++nt) {
            int n = wv * 32 + nt * 16 + fr;
#pragma unroll
            for (int r = 0; r < 4; ++r) {
                int m = mt * 16 + quad * 4 + r;
                float z1 = acc1[mt][nt][r] + bias1[nt];
                float z2 = acc2[mt][nt][r] + bias2[nt];
                float sg = __builtin_amdgcn_rcpf(1.0f + __expf(-z2));
                A_s[m * 264 + n] = __float2bfloat16(z1 * sg);
            }
        }
    __syncthreads();                               // g complete
    const bf16* Hr = Hb + (size_t)(m0 + rr) * HDIM + qd * 32;
    float rv[32];
    float sum = 0.f, sq = 0.f;
#pragma unroll
    for (int i4 = 0; i4 < 4; ++i4) {
        uint4 gv = *(uint4*)&A_s[rr * 264 + qd * 32 + i4 * 8];
        uint4 hv4 = *(const uint4*)&Hr[i4 * 8];
        const bf16* gp = (const bf16*)&gv;
        const bf16* hp = (const bf16*)&hv4;
#pragma unroll
        for (int e = 0; e < 8; ++e) {
            float v = __bfloat162float(gp[e]) + __bfloat162float(hp[e]);
            rv[i4 * 8 + e] = v; sum += v; sq += v * v;
        }
    }
    red[0][qd][rr] = sum; red[1][qd][rr] = sq;
    __syncthreads();
    if (tid < 64) {
        float s = 0.f, s2 = 0.f;
#pragma unroll
        for (int q = 0; q < 8; ++q) { s += red[0][q][tid]; s2 += red[1][q][tid]; }
        float mean = s * (1.f / HDIM);
        float var = s2 * (1.f / HDIM) - mean * mean;
        stat[0][tid] = mean; stat[1][tid] = rsqrtf(var + 1e-5f);
    }
    __syncthreads();
    float mean = stat[0][rr], rstd = stat[1][rr];
#pragma unroll
    for (int j = 0; j < 32; ++j)
        rv[j] = (rv[j] - mean) * rstd * w_s[qd * 32 + j] + b_s[qd * 32 + j];
    if (mode == 0) {
        // packed bf16 H write (new residual = LN out)
        bf16* Hw = Hb + (size_t)(m0 + rr) * HDIM + qd * 32;
#pragma unroll
        for (int j = 0; j < 32; j += 8) {
            unsigned int pk[4];
#pragma unroll
            for (int e = 0; e < 4; ++e)
                pk[e] = (unsigned int)f2bu(rv[j + 2 * e]) | ((unsigned int)f2bu(rv[j + 2 * e + 1]) << 16);
            *(uint4*)&Hw[j] = *(uint4*)pk;
        }
        // direct Ut store: [h][m], lanes rr 0..63 contiguous -> full 128B line per wave store
        bf16* Up = Ut + (size_t)(qd * 32) * M_ROWS + m0 + rr;
#pragma unroll
        for (int j = 0; j < 32; ++j)
            Up[(size_t)j * M_ROWS] = __float2bfloat16(rv[j]);
    } else {
        // decoder: stage dec_w over dead A_s (g fully consumed into rv, fenced by red barrier)
        float* dwf = (float*)A_s;                  // 2560 floats = 10240 B
        for (int e = tid; e < HDIM * DOUT; e += 512) dwf[e] = dw[e];
        __syncthreads();
        float part[DOUT];
#pragma unroll
        for (int o = 0; o < DOUT; ++o) part[o] = 0.f;
#pragma unroll
        for (int j = 0; j < 32; ++j) {
            float tv = rv[j];
            const float* dr = &dwf[(qd * 32 + j) * DOUT];
#pragma unroll
            for (int o = 0; o < DOUT; ++o) part[o] = fmaf(tv, dr[o], part[o]);
        }
        // reduce across the 8 qd-groups, 2 outputs per pass via red
#pragma unroll
        for (int oc = 0; oc < 5; ++oc) {
            red[0][qd][rr] = part[2 * oc];
            red[1][qd][rr] = part[2 * oc + 1];
            __syncthreads();
            if (tid < 128) {
                int rl = tid & 63, ph = tid >> 6;
                float s = 0.f;
#pragma unroll
                for (int q = 0; q < 8; ++q) s += red[ph][q][rl];
                int o = 2 * oc + ph;
                outp[(size_t)(m0 + rl) * DOUT + o] = s + db_s[o];
            }
            __syncthreads();
        }
    }
}

extern "C" void kernel_launch(void* const* d_in, const int* in_sizes, int n_in,
                              void* d_out, int out_size, void* d_ws, size_t ws_size,
                              hipStream_t stream) {
    const float* x        = (const float*)d_in[0];
    const float* enc_w    = (const float*)d_in[1];
    const float* enc_b    = (const float*)d_in[2];
    const float* log_dt   = (const float*)d_in[3];
    const float* A_re_log = (const float*)d_in[4];
    const float* A_im     = (const float*)d_in[5];
    const float* B_re     = (const float*)d_in[6];
    const float* B_im     = (const float*)d_in[7];
    const float* C_re     = (const float*)d_in[8];
    const float* C_im     = (const float*)d_in[9];
    const float* Dp       = (const float*)d_in[10];
    const float* ln_w     = (const float*)d_in[11];
    const float* ln_b     = (const float*)d_in[12];
    const float* out_w    = (const float*)d_in[13];
    const float* out_b    = (const float*)d_in[14];
    const float* dec_w    = (const float*)d_in[15];
    const float* dec_b    = (const float*)d_in[16];
    float* outp = (float*)d_out;

    float* w = (float*)d_ws;
    const size_t PWE = (size_t)NLAYERS * NSTATE * HDIM;   // 32768
    const size_t MH  = (size_t)M_ROWS * HDIM;             // 8388608
    const size_t VME = (size_t)NLAYERS * HDIM * 64 * 64;  // 4M elems/matrix
    float2* PA64 = (float2*)(w + 4 * PWE);                // 256 KB
    float*  Td   = w + 6 * PWE;                           // 270 KB
    bf16*   Hbuf = (bf16*)(Td + (size_t)NLAYERS * HDIM * 66);  // 16.7 MB bf16
    bf16*   Ut   = Hbuf + MH;                             // 16.7 MB
    bf16*   Yt   = Ut + MH;                               // 16.7 MB
    bf16*   Wt   = Yt + MH;                               // 1 MB (G buffer eliminated)
    bf16*   Wet  = Wt + (size_t)NLAYERS * 512 * HDIM;     // 64 KB
    bf16*   Vg   = Wet + (size_t)HDIM * DIN;              // 8 MB (all layers)
    bf16*   Mg   = Vg + VME;                              // 8 MB (all layers)

    {
        int total = VMB_ + TDB_ + PAB_ + WCB_ + HDIM * DIN / 256;
        k_setup<<<total, 256, 0, stream>>>(log_dt, A_re_log, A_im, B_re, B_im, C_re, C_im,
                                           out_w, enc_w, Td, Vg, Mg, PA64, Wt, Wet);
    }

    dim3 ge(M_ROWS / 128, HDIM / 64);
    k_enc2<<<ge, 256, 0, stream>>>(x, Wet, enc_b, Hbuf, Ut);

    dim3 gconv(HDIM, NBC / 128);
    for (int layer = 0; layer < NLAYERS; ++layer) {
        const float2* pal = PA64 + (size_t)layer * NSTATE * HDIM;
        const float*  tdl = Td + (size_t)layer * HDIM * 66;
        const bf16*   vgl = Vg + (size_t)layer * HDIM * 64 * 64;
        const bf16*   mgl = Mg + (size_t)layer * HDIM * 64 * 64;
        k_conv<<<gconv, 256, 0, stream>>>(Ut, vgl, mgl, tdl, pal, Dp + layer * HDIM, Yt);
        k_gluln<<<M_ROWS / 64, 512, 0, stream>>>(Yt, Wt + (size_t)layer * 512 * HDIM,
                                                 out_b + layer * 2 * HDIM, Hbuf,
                                                 ln_w + layer * HDIM, ln_b + layer * HDIM,
                                                 Ut, dec_w, dec_b, outp,
                                                 layer == NLAYERS - 1 ? 1 : 0);
    }
}

// Round 9
// 283.732 us; speedup vs baseline: 1.2407x; 1.0444x over previous
//
#include <hip/hip_runtime.h>
#include <hip/hip_bf16.h>
#include <math.h>

#define B_SZ    32
#define LSEQ    1024
#define DIN     128
#define HDIM    256
#define NLAYERS 4
#define NSTATE  32
#define DOUT    10
#define M_ROWS  (B_SZ*LSEQ)   // 32768
#define CH      64            // scan chunk length
#define NCH     (LSEQ/CH)     // 16 chunks
#define NBC     (B_SZ*NCH)    // 512 chunk-columns

typedef __hip_bfloat16 bf16;
typedef __attribute__((ext_vector_type(8))) short bf16x8;
typedef __attribute__((ext_vector_type(4))) float f32x4;

__device__ __forceinline__ unsigned short f2bu(float x) {
    bf16 b = __float2bfloat16(x);
    return *(unsigned short*)&b;
}
__device__ __forceinline__ float bu2f(unsigned short u) {
    bf16 b = *(bf16*)&u;
    return __bfloat162float(b);
}

// inline S4D discretization: returns (dtAre, dtAim, Wre, Wim)
// r9: fast transcendentals (__expf/__cosf/__sinf) with explicit range reduction — all consumers
// store bf16, so ~1e-6 relative error is invisible; saves ~150 instrs/call at 2M+ call sites.
__device__ __forceinline__ float4 s4param(const float* __restrict__ log_dt,
                                          const float* __restrict__ A_re_log,
                                          const float* __restrict__ A_im,
                                          const float* __restrict__ B_re,
                                          const float* __restrict__ B_im,
                                          const float* __restrict__ C_re,
                                          const float* __restrict__ C_im,
                                          int layer, int h, int n) {
    const float inv2pi = 0.15915494309189535f;
    const float twopi  = 6.283185307179586f;
    int hn = layer * HDIM + h;
    int idx = hn * NSTATE + n;
    float dt   = __expf(log_dt[hn]);
    float Are  = -__expf(A_re_log[idx]);
    float Aim  = A_im[idx];
    float dtAre = dt * Are, dtAim = dt * Aim;
    float ea   = __expf(dtAre);
    float pr0  = dtAim * inv2pi;
    float th0  = (pr0 - floorf(pr0)) * twopi;    // |dtAim| <= ~10 rad, reduced to [0,2pi)
    float dAre = ea * __cosf(th0), dAim = ea * __sinf(th0);
    float nre = dAre - 1.0f, nim = dAim;
    float inv = 1.0f / (Are * Are + Aim * Aim);
    float tre = (nre * Are + nim * Aim) * inv;
    float tim = (nim * Are - nre * Aim) * inv;
    float Brv = B_re[idx], Biv = B_im[idx];
    float dBre = Brv * tre - Biv * tim;
    float dBim = Brv * tim + Biv * tre;
    float Crv = C_re[idx], Civ = C_im[idx];
    float Wre = Crv * dBre - Civ * dBim;
    float Wim = Crv * dBim + Civ * dBre;
    return make_float4(dtAre, dtAim, Wre, Wim);
}

// ---------------- ONE setup kernel: V/M, Td, PA64, weight transposes ----------------
// r3: Vg and Wt stored FRAGMENT-MAJOR so consumer wave-loads are base+lane*16B coalesced.
#define VMB_ (NLAYERS*HDIM*64*32/256)    // 8192
#define TDB_ ((NLAYERS*HDIM*66+255)/256) // 264
#define PAB_ (NLAYERS*NSTATE*HDIM/256)   // 128
#define WCB_ (NLAYERS*512*256/256)       // 2048
__global__ void k_setup(const float* __restrict__ log_dt, const float* __restrict__ A_re_log,
                        const float* __restrict__ A_im, const float* __restrict__ B_re,
                        const float* __restrict__ B_im, const float* __restrict__ C_re,
                        const float* __restrict__ C_im, const float* __restrict__ out_w,
                        const float* __restrict__ enc_w, float* __restrict__ Td,
                        bf16* __restrict__ Vg, bf16* __restrict__ Mg,
                        float2* __restrict__ PA64, bf16* __restrict__ Wt,
                        bf16* __restrict__ Wet) {
    const float inv2pi = 0.15915494309189535f;
    const float twopi  = 6.283185307179586f;
    int bx = blockIdx.x;
    if (bx < VMB_) {                                 // V/M pair-elements
        int gid = bx * 256 + threadIdx.x;
        int jp = (gid & 31) * 2;
        int row = gid >> 5;                          // ((layer*256+h)*64)+comp
        int comp = row & 63, h = (row >> 6) & 255, layer = row >> 14;
        int n = comp >> 1, isIm = comp & 1;
        float4 q = s4param(log_dt, A_re_log, A_im, B_re, B_im, C_re, C_im, layer, h, n);
        unsigned int vpk = 0, mpk = 0;
#pragma unroll
        for (int e = 0; e < 2; ++e) {
            int j = jp + e;
            float dv = (float)(63 - j);
            float magv = __expf(dv * q.x);
            float pr = dv * q.y * inv2pi;
            float th = (pr - floorf(pr)) * twopi;
            float c = __cosf(th), s = __sinf(th);
            float vre = magv * (q.z * c - q.w * s);
            float vim = magv * (q.z * s + q.w * c);
            vpk |= (unsigned int)f2bu(isIm ? vim : vre) << (16 * e);
            float dm = (float)(j + 1);
            float magm = __expf(dm * q.x);
            float pr2 = dm * q.y * inv2pi;
            float th2 = (pr2 - floorf(pr2)) * twopi;
            float mv = isIm ? (-2.f * magm * __sinf(th2)) : (2.f * magm * __cosf(th2));
            mpk |= (unsigned int)f2bu(mv) << (16 * e);
        }
        // V fragment-major within (layer,h) 64x64 block
        {
            int mtv = comp >> 4, frv = comp & 15;
            int ksv = jp >> 5, qdv = (jp >> 3) & 3, ev = jp & 7;
            size_t voff = (size_t)(layer * 256 + h) * 4096
                        + ((size_t)((mtv * 2 + ksv) * 64) + qdv * 16 + frv) * 8 + ev;
            ((unsigned int*)Vg)[voff >> 1] = vpk;    // jp even -> voff even
        }
        ((unsigned int*)Mg)[(size_t)row * 32 + (jp >> 1)] = mpk;   // M row-major (LDS-staged)
    } else if (bx < VMB_ + TDB_) {                   // Td
        int gid = (bx - VMB_) * 256 + threadIdx.x;
        int d = gid % 66;
        int lh = gid / 66;
        if (lh < NLAYERS * HDIM && d < 65) {
            int layer = lh >> 8, h = lh & 255;
            float fd = (float)d;
            float acc = 0.f;
            for (int n = 0; n < NSTATE; ++n) {
                float4 q = s4param(log_dt, A_re_log, A_im, B_re, B_im, C_re, C_im, layer, h, n);
                float mag = __expf(fd * q.x);
                float pr = fd * q.y * inv2pi;
                float th = (pr - floorf(pr)) * twopi;
                acc += mag * (q.z * __cosf(th) - q.w * __sinf(th));
            }
            Td[(size_t)lh * 66 + d] = 2.f * acc;
        }
    } else if (bx < VMB_ + TDB_ + PAB_) {            // PA64 = dA^64 per (layer,n,h)
        int idx = (bx - VMB_ - TDB_) * 256 + threadIdx.x;
        int h = idx & 255, n = (idx >> 8) & 31, layer = idx >> 13;
        float4 q = s4param(log_dt, A_re_log, A_im, B_re, B_im, C_re, C_im, layer, h, n);
        float e64 = __expf(64.0f * q.x);
        float ph  = 64.0f * q.y;
        float pr  = ph * inv2pi;
        float th  = (pr - floorf(pr)) * twopi;       // explicit reduction: |ph| up to ~620 rad
        PA64[idx] = make_float2(e64 * __cosf(th), e64 * __sinf(th));
    } else if (bx < VMB_ + TDB_ + PAB_ + WCB_) {     // Wt fragment-major
        int idx = (bx - VMB_ - TDB_ - PAB_) * 256 + threadIdx.x;
        int k = idx & 255;
        int n = (idx >> 8) & 511;
        int layer = idx >> 17;
        // [nb=n>>4][ks=k>>5][quad=(k>>3)&3][fr=n&15][e=k&7]
        size_t off = (size_t)layer * (512 * 256)
                   + ((size_t)((n >> 4) * 8 + (k >> 5)) * 64 + (((k >> 3) & 3) * 16 + (n & 15))) * 8
                   + (k & 7);
        Wt[off] = __float2bfloat16(out_w[((size_t)(layer * 256 + k)) * 512 + n]);
    } else {                                         // Wet transpose
        int idx = (bx - VMB_ - TDB_ - PAB_ - WCB_) * 256 + threadIdx.x;
        int k = idx & 127, n = idx >> 7;
        Wet[idx] = __float2bfloat16(enc_w[(size_t)k * HDIM + n]);
    }
}

// ---------------- encoder GEMM (bf16 MFMA): H(bf16) = X@We + b, + transposed Ut ----------------
__global__ __launch_bounds__(256) void k_enc2(const float* __restrict__ X, const bf16* __restrict__ Wet,
                                              const float* __restrict__ bias, bf16* __restrict__ H,
                                              bf16* __restrict__ Ut) {
    __shared__ bf16 A_s[128 * 136];
    __shared__ bf16 B_s[64 * 136];
    int tid = threadIdx.x;
    int lane = tid & 63, wv = tid >> 6, quad = lane >> 4, fr = lane & 15;
    int m0 = blockIdx.x * 128, n0 = blockIdx.y * 64;
#pragma unroll
    for (int i = 0; i < 16; ++i) {               // stage X fp32 -> bf16 [m][k], packed u32 writes
        int q = tid + i * 256, row = q >> 5, seg = q & 31;
        float4 v = *(const float4*)&X[(size_t)(m0 + row) * DIN + seg * 4];
        unsigned int p0 = (unsigned int)f2bu(v.x) | ((unsigned int)f2bu(v.y) << 16);
        unsigned int p1 = (unsigned int)f2bu(v.z) | ((unsigned int)f2bu(v.w) << 16);
        *(unsigned int*)&A_s[row * 136 + seg * 4]     = p0;
        *(unsigned int*)&A_s[row * 136 + seg * 4 + 2] = p1;
    }
#pragma unroll
    for (int i = 0; i < 4; ++i) {                // stage Wet [n][k]
        int q = tid + i * 256, row = q >> 4, seg = q & 15;
        *(uint4*)&B_s[row * 136 + seg * 8] = *(const uint4*)&Wet[(size_t)(n0 + row) * DIN + seg * 8];
    }
    __syncthreads();
    f32x4 acc[2][4];
#pragma unroll
    for (int mt = 0; mt < 2; ++mt)
#pragma unroll
        for (int nt = 0; nt < 4; ++nt) acc[mt][nt] = (f32x4){0.f, 0.f, 0.f, 0.f};
#pragma unroll
    for (int ks = 0; ks < 4; ++ks) {
        bf16x8 a[2], b[4];
#pragma unroll
        for (int mt = 0; mt < 2; ++mt)
            a[mt] = *(const bf16x8*)&A_s[(wv * 32 + mt * 16 + fr) * 136 + ks * 32 + quad * 8];
#pragma unroll
        for (int nt = 0; nt < 4; ++nt)
            b[nt] = *(const bf16x8*)&B_s[(nt * 16 + fr) * 136 + ks * 32 + quad * 8];
#pragma unroll
        for (int mt = 0; mt < 2; ++mt)
#pragma unroll
            for (int nt = 0; nt < 4; ++nt)
                acc[mt][nt] = __builtin_amdgcn_mfma_f32_16x16x32_bf16(a[mt], b[nt], acc[mt][nt], 0, 0, 0);
    }
    __syncthreads();                             // B_s reuse as transpose bounce
#pragma unroll
    for (int mt = 0; mt < 2; ++mt)
#pragma unroll
        for (int nt = 0; nt < 4; ++nt) {
            int n = n0 + nt * 16 + fr;
            float bv = bias[n];
#pragma unroll
            for (int r = 0; r < 4; ++r) {
                int m = m0 + wv * 32 + mt * 16 + quad * 4 + r;
                float hv = acc[mt][nt][r] + bv;
                bf16 hb = __float2bfloat16(hv);
                H[(size_t)m * HDIM + n] = hb;
                B_s[(nt * 16 + fr) * 136 + (wv * 32 + mt * 16 + quad * 4 + r)] = hb;
            }
        }
    __syncthreads();
#pragma unroll
    for (int i = 0; i < 4; ++i) {                // coalesced Ut store [h][m]
        int q = tid + i * 256, row = q >> 4, seg = q & 15;
        *(uint4*)&Ut[(size_t)(n0 + row) * M_ROWS + m0 + seg * 8] = *(uint4*)&B_s[row * 136 + seg * 8];
    }
}

// ---------------- fused conv (r8 structure, unchanged) ----------------
__global__ __launch_bounds__(256) void k_conv(const bf16* __restrict__ Ut,
                                              const bf16* __restrict__ Vg,
                                              const bf16* __restrict__ Mg,
                                              const float* __restrict__ Tdl,
                                              const float2* __restrict__ PA,
                                              const float* __restrict__ Dw,
                                              bf16* __restrict__ Yt) {
    __shared__ bf16 A_s[64 * 136];               // [l][k2], k2<64: T, k2>=64: M
    __shared__ bf16 Eo_s[128 * 72];              // [bc][comp]: E, then carries, then o_s
    int h = blockIdx.x, bc0 = blockIdx.y * 128;
    int tid = threadIdx.x;
    int lane = tid & 63, wv = tid >> 6, quad = lane >> 4, fr = lane & 15;
    const float* Tdh = Tdl + (size_t)h * 66;
    const bf16* Uh = Ut + (size_t)h * M_ROWS + (size_t)bc0 * 64;
    // prologue: ALL global operands issued up front (batched, independent)
    bf16x8 va[2][4], ub[2][2];
#pragma unroll
    for (int ks = 0; ks < 2; ++ks) {
#pragma unroll
        for (int mt = 0; mt < 4; ++mt)           // fragment-major Vg: coalesced
            va[ks][mt] = *(const bf16x8*)&Vg[(size_t)h * 4096 + ((size_t)((mt * 2 + ks) * 64) + lane) * 8];
#pragma unroll
        for (int nf = 0; nf < 2; ++nf)
            ub[ks][nf] = *(const bf16x8*)&Uh[(size_t)(wv * 32 + nf * 16 + fr) * 64 + ks * 32 + quad * 8];
    }
    float2 pa = PA[(tid & 31) * HDIM + h];       // scan coefficient (thread = (bl, n))
    float Dv = Dw[h];
#pragma unroll
    for (int i = 0; i < 2; ++i) {                // stage M transposed into A_s cols 64..127
        int q = tid + i * 256, comp = q >> 3, seg = q & 7;
        uint4 v = *(const uint4*)&Mg[((size_t)h * 64 + comp) * 64 + seg * 8];
        const bf16* pv = (const bf16*)&v;
#pragma unroll
        for (int e = 0; e < 8; ++e) A_s[(seg * 8 + e) * 136 + 64 + comp] = pv[e];
    }
#pragma unroll
    for (int i = 0; i < 8; ++i) {                // Toeplitz T fill, packed u32 writes
        int q = tid + i * 256;                   // q in [0,2048): l = q>>5, jp = (q&31)*2
        int l = q >> 5, jp = (q & 31) * 2;
        int d0 = l - jp, d1 = d0 - 1;
        unsigned int pk = (unsigned int)f2bu(d0 >= 0 ? Tdh[d0] : 0.f)
                        | ((unsigned int)f2bu(d1 >= 0 ? Tdh[d1] : 0.f) << 16);
        *(unsigned int*)&A_s[l * 136 + jp] = pk;
    }
    f32x4 eacc[4][2];
#pragma unroll
    for (int mt = 0; mt < 4; ++mt)
#pragma unroll
        for (int nf = 0; nf < 2; ++nf) eacc[mt][nf] = (f32x4){0.f, 0.f, 0.f, 0.f};
#pragma unroll
    for (int ks = 0; ks < 2; ++ks)
#pragma unroll
        for (int mt = 0; mt < 4; ++mt)
#pragma unroll
            for (int nf = 0; nf < 2; ++nf)
                eacc[mt][nf] = __builtin_amdgcn_mfma_f32_16x16x32_bf16(va[ks][mt], ub[ks][nf], eacc[mt][nf], 0, 0, 0);
#pragma unroll
    for (int mt = 0; mt < 4; ++mt)               // E -> Eo_s [bc][comp]; wave-local rows
#pragma unroll
        for (int nf = 0; nf < 2; ++nf) {
            int bc = wv * 32 + nf * 16 + fr;
#pragma unroll
            for (int r = 0; r < 4; r += 2) {
                int comp = mt * 16 + quad * 4 + r;
                *(unsigned int*)&Eo_s[bc * 72 + comp] =
                    (unsigned int)f2bu(eacc[mt][nf][r]) | ((unsigned int)f2bu(eacc[mt][nf][r + 1]) << 16);
            }
        }
    {   // wave-local carry scan (no barrier: reads/writes only this wave's rows, program-ordered)
        int bl = tid >> 5, n = tid & 31;         // bl in {2wv, 2wv+1} -> rows [32wv, 32wv+32)
        unsigned int ev[NCH];
#pragma unroll
        for (int c = 0; c < NCH; ++c)            // batched independent LDS reads (pipelined)
            ev[c] = *(unsigned int*)&Eo_s[(bl * NCH + c) * 72 + 2 * n];
        float cr = 0.f, ci = 0.f;
#pragma unroll
        for (int c = 0; c < NCH; ++c) {          // pure-register recurrence
            unsigned int wvp = (unsigned int)f2bu(cr) | ((unsigned int)f2bu(ci) << 16);
            float er = bu2f((unsigned short)(ev[c] & 0xffff));
            float ei = bu2f((unsigned short)(ev[c] >> 16));
            float nr = fmaf(pa.x, cr, fmaf(-pa.y, ci, er));
            ci = fmaf(pa.x, ci, fmaf(pa.y, cr, ei));
            cr = nr;
            ev[c] = wvp;
        }
#pragma unroll
        for (int c = 0; c < NCH; ++c)            // batched independent LDS writes
            *(unsigned int*)&Eo_s[(bl * NCH + c) * 72 + 2 * n] = ev[c];
    }
    __syncthreads();                             // A_s (cross-wave) + carries ready
    // prefetch epilogue u-gathers (independent of MFMA results; L2-hot)
    uint2 uvp[4][2];
#pragma unroll
    for (int mt = 0; mt < 4; ++mt)
#pragma unroll
        for (int nf = 0; nf < 2; ++nf)
            uvp[mt][nf] = *(const uint2*)&Uh[(size_t)(wv * 32 + nf * 16 + fr) * 64 + mt * 16 + quad * 4];
    f32x4 acc[4][2];
#pragma unroll
    for (int mt = 0; mt < 4; ++mt)
#pragma unroll
        for (int nf = 0; nf < 2; ++nf) acc[mt][nf] = (f32x4){0.f, 0.f, 0.f, 0.f};

#define LDAB(AA, BB, KS) do { \
    _Pragma("unroll") \
    for (int mt = 0; mt < 4; ++mt) \
        AA[mt] = *(const bf16x8*)&A_s[(mt * 16 + fr) * 136 + (KS) * 32 + quad * 8]; \
    _Pragma("unroll") \
    for (int nf = 0; nf < 2; ++nf) \
        BB[nf] = ((KS) < 2) ? ub[(KS) & 1][nf] \
               : *(const bf16x8*)&Eo_s[(wv * 32 + nf * 16 + fr) * 72 + ((KS) & 1) * 32 + quad * 8]; \
    } while (0)
#define MFMAC(AA, BB) do { \
    _Pragma("unroll") \
    for (int mt = 0; mt < 4; ++mt) \
        _Pragma("unroll") \
        for (int nf = 0; nf < 2; ++nf) \
            acc[mt][nf] = __builtin_amdgcn_mfma_f32_16x16x32_bf16(AA[mt], BB[nf], acc[mt][nf], 0, 0, 0); \
    } while (0)

    {
        bf16x8 aA[4], bA[2], aB[4], bB[2];
        LDAB(aA, bA, 0);
        LDAB(aB, bB, 1);
        MFMAC(aA, bA);
        LDAB(aA, bA, 2);
        MFMAC(aB, bB);
        LDAB(aB, bB, 3);
        MFMAC(aA, bA);
        MFMAC(aB, bB);
    }
#undef LDAB
#undef MFMAC

#pragma unroll
    for (int mt = 0; mt < 4; ++mt)
#pragma unroll
        for (int nf = 0; nf < 2; ++nf) {
            int bcl = wv * 32 + nf * 16 + fr;
            const bf16* up = (const bf16*)&uvp[mt][nf];
#pragma unroll
            for (int r = 0; r < 4; ++r) {
                int l = mt * 16 + quad * 4 + r;
                float u = __bfloat162float(up[r]);
                float v = fmaf(Dv, u, acc[mt][nf][r]);
                float z2 = 1.5957691216057308f * (v + 0.044715f * v * v * v);
                float sg = __builtin_amdgcn_rcpf(1.f + __expf(-z2));
                Eo_s[bcl * 72 + l] = __float2bfloat16(v * sg);   // own rows only
            }
        }
    __syncthreads();                             // cross-wave for transposed store
#pragma unroll
    for (int i = 0; i < 4; ++i) {                // coalesced Yt store
        int q = tid + i * 256, row = q >> 3, c8 = q & 7;
        *(uint4*)&Yt[(size_t)h * M_ROWS + (size_t)(bc0 + row) * 64 + c8 * 8] =
            *(uint4*)&Eo_s[row * 72 + c8 * 8];
    }
}

// ---------------- FUSED output GEMM + GLU + residual + LayerNorm (+ decoder on last layer) ----
// r7 structure; r9: pack rv->bf16 ONCE and reuse the packed words for both the H write and the
// Ut store (saves 32 cvts/thread in the epilogue).
__global__ __launch_bounds__(512, 4) void k_gluln(const bf16* __restrict__ Yt,
                                                  const bf16* __restrict__ Wt,
                                                  const float* __restrict__ wb,
                                                  bf16* __restrict__ Hb,
                                                  const float* __restrict__ w,
                                                  const float* __restrict__ bbias,
                                                  bf16* __restrict__ Ut,
                                                  const float* __restrict__ dw,
                                                  const float* __restrict__ db,
                                                  float* __restrict__ outp, int mode) {
    __shared__ __align__(16) bf16 A_s[64 * 264];   // A tile [m][k]; then g [m][n]; mode1: dw overlay
    __shared__ float red[2][8][64];
    __shared__ float stat[2][64];
    __shared__ float w_s[256], b_s[256];
    __shared__ float db_s[16];
    int tid = threadIdx.x;
    int lane = tid & 63, wv = tid >> 6;            // wv in [0,8)
    int quad = lane >> 4, fr = lane & 15;
    int m0 = blockIdx.x * 64;
    int rr = tid & 63, qd = tid >> 6;              // LN coords: row 0..63, col-seg 0..7
    if (tid < 256) { w_s[tid] = w[tid]; b_s[tid] = bbias[tid]; }
    if (mode == 1 && tid < DOUT) db_s[tid] = db[tid];
    float bias1[2], bias2[2];
#pragma unroll
    for (int nt = 0; nt < 2; ++nt) {               // GLU biases -> regs (L2-hot)
        bias1[nt] = wb[wv * 32 + nt * 16 + fr];
        bias2[nt] = wb[HDIM + wv * 32 + nt * 16 + fr];
    }
    {                                              // stage A: Yt[k][m] -> A_s[m][k] (reg transpose)
        int mg = tid & 15, hg = tid >> 4;          // mg: 4-m group [0,16); hg: k-octet [0,32)
        uint2 rowv[8];
#pragma unroll
        for (int e = 0; e < 8; ++e)
            rowv[e] = *(const uint2*)&Yt[(size_t)(hg * 8 + e) * M_ROWS + m0 + mg * 4];
#pragma unroll
        for (int j = 0; j < 4; ++j) {
            unsigned int pk[4];
#pragma unroll
            for (int k2 = 0; k2 < 4; ++k2) {
                unsigned int lo = ((const unsigned short*)&rowv[2 * k2])[j];
                unsigned int hi = ((const unsigned short*)&rowv[2 * k2 + 1])[j];
                pk[k2] = lo | (hi << 16);
            }
            *(uint4*)&A_s[(mg * 4 + j) * 264 + hg * 8] = *(uint4*)pk;
        }
    }
    f32x4 acc1[4][2], acc2[4][2];                  // [m-frag][n-frag], both GLU halves
#pragma unroll
    for (int mt = 0; mt < 4; ++mt)
#pragma unroll
        for (int nt = 0; nt < 2; ++nt) {
            acc1[mt][nt] = (f32x4){0.f, 0.f, 0.f, 0.f};
            acc2[mt][nt] = (f32x4){0.f, 0.f, 0.f, 0.f};
        }
    __syncthreads();

    // B frags: wave wv -> n-blocks nb = wv*2+nt (half1), 16+wv*2+nt (half2)
#define LOAD_B(d1, d2, KS) do { \
    _Pragma("unroll") \
    for (int nt = 0; nt < 2; ++nt) { \
        d1[nt] = *(const bf16x8*)&Wt[((size_t)((wv * 2 + nt) * 8 + (KS)) * 64 + lane) * 8]; \
        d2[nt] = *(const bf16x8*)&Wt[((size_t)((16 + wv * 2 + nt) * 8 + (KS)) * 64 + lane) * 8]; \
    } } while (0)

#define DO_MFMA(bb1, bb2, KS) do { \
    bf16x8 afr[4]; \
    _Pragma("unroll") \
    for (int mt = 0; mt < 4; ++mt) \
        afr[mt] = *(const bf16x8*)&A_s[(mt * 16 + fr) * 264 + (KS) * 32 + quad * 8]; \
    _Pragma("unroll") \
    for (int mt = 0; mt < 4; ++mt) \
        _Pragma("unroll") \
        for (int nt = 0; nt < 2; ++nt) { \
            acc1[mt][nt] = __builtin_amdgcn_mfma_f32_16x16x32_bf16(afr[mt], bb1[nt], acc1[mt][nt], 0, 0, 0); \
            acc2[mt][nt] = __builtin_amdgcn_mfma_f32_16x16x32_bf16(afr[mt], bb2[nt], acc2[mt][nt], 0, 0, 0); \
        } } while (0)

    {
        bf16x8 p1[2], p2[2], q1[2], q2[2];
        LOAD_B(p1, p2, 0);
#pragma unroll
        for (int kp = 0; kp < 4; ++kp) {
            LOAD_B(q1, q2, 2 * kp + 1);
            DO_MFMA(p1, p2, 2 * kp);
            if (kp < 3) LOAD_B(p1, p2, 2 * kp + 2);
            DO_MFMA(q1, q2, 2 * kp + 1);
        }
    }
#undef LOAD_B
#undef DO_MFMA

    __syncthreads();                               // A_s dead as A-tile; reuse for g [m][n]
#pragma unroll
    for (int mt = 0; mt < 4; ++mt)
#pragma unroll
        for (int nt = 0; nt < 2; ++nt) {
            int n = wv * 32 + nt * 16 + fr;
#pragma unroll
            for (int r = 0; r < 4; ++r) {
                int m = mt * 16 + quad * 4 + r;
                float z1 = acc1[mt][nt][r] + bias1[nt];
                float z2 = acc2[mt][nt][r] + bias2[nt];
                float sg = __builtin_amdgcn_rcpf(1.0f + __expf(-z2));
                A_s[m * 264 + n] = __float2bfloat16(z1 * sg);
            }
        }
    __syncthreads();                               // g complete
    const bf16* Hr = Hb + (size_t)(m0 + rr) * HDIM + qd * 32;
    float rv[32];
    float sum = 0.f, sq = 0.f;
#pragma unroll
    for (int i4 = 0; i4 < 4; ++i4) {
        uint4 gv = *(uint4*)&A_s[rr * 264 + qd * 32 + i4 * 8];
        uint4 hv4 = *(const uint4*)&Hr[i4 * 8];
        const bf16* gp = (const bf16*)&gv;
        const bf16* hp = (const bf16*)&hv4;
#pragma unroll
        for (int e = 0; e < 8; ++e) {
            float v = __bfloat162float(gp[e]) + __bfloat162float(hp[e]);
            rv[i4 * 8 + e] = v; sum += v; sq += v * v;
        }
    }
    red[0][qd][rr] = sum; red[1][qd][rr] = sq;
    __syncthreads();
    if (tid < 64) {
        float s = 0.f, s2 = 0.f;
#pragma unroll
        for (int q = 0; q < 8; ++q) { s += red[0][q][tid]; s2 += red[1][q][tid]; }
        float mean = s * (1.f / HDIM);
        float var = s2 * (1.f / HDIM) - mean * mean;
        stat[0][tid] = mean; stat[1][tid] = rsqrtf(var + 1e-5f);
    }
    __syncthreads();
    float mean = stat[0][rr], rstd = stat[1][rr];
#pragma unroll
    for (int j = 0; j < 32; ++j)
        rv[j] = (rv[j] - mean) * rstd * w_s[qd * 32 + j] + b_s[qd * 32 + j];
    if (mode == 0) {
        // pack once; reuse for H write (uint4) and Ut store (short extract)
        unsigned int pkv[16];
#pragma unroll
        for (int p = 0; p < 16; ++p)
            pkv[p] = (unsigned int)f2bu(rv[2 * p]) | ((unsigned int)f2bu(rv[2 * p + 1]) << 16);
        bf16* Hw = Hb + (size_t)(m0 + rr) * HDIM + qd * 32;
#pragma unroll
        for (int j8 = 0; j8 < 4; ++j8)
            *(uint4*)&Hw[j8 * 8] = *(uint4*)&pkv[j8 * 4];
        // direct Ut store: [h][m], lanes rr 0..63 contiguous -> full 128B line per wave store
        bf16* Up = Ut + (size_t)(qd * 32) * M_ROWS + m0 + rr;
#pragma unroll
        for (int j = 0; j < 32; ++j) {
            unsigned int word = pkv[j >> 1];
            unsigned short hv = (j & 1) ? (unsigned short)(word >> 16)
                                        : (unsigned short)(word & 0xffff);
            *(unsigned short*)&Up[(size_t)j * M_ROWS] = hv;
        }
    } else {
        // decoder: stage dec_w over dead A_s (g fully consumed into rv, fenced by red barrier)
        float* dwf = (float*)A_s;                  // 2560 floats = 10240 B
        for (int e = tid; e < HDIM * DOUT; e += 512) dwf[e] = dw[e];
        __syncthreads();
        float part[DOUT];
#pragma unroll
        for (int o = 0; o < DOUT; ++o) part[o] = 0.f;
#pragma unroll
        for (int j = 0; j < 32; ++j) {
            float tv = rv[j];
            const float* dr = &dwf[(qd * 32 + j) * DOUT];
#pragma unroll
            for (int o = 0; o < DOUT; ++o) part[o] = fmaf(tv, dr[o], part[o]);
        }
        // reduce across the 8 qd-groups, 2 outputs per pass via red
#pragma unroll
        for (int oc = 0; oc < 5; ++oc) {
            red[0][qd][rr] = part[2 * oc];
            red[1][qd][rr] = part[2 * oc + 1];
            __syncthreads();
            if (tid < 128) {
                int rl = tid & 63, ph = tid >> 6;
                float s = 0.f;
#pragma unroll
                for (int q = 0; q < 8; ++q) s += red[ph][q][rl];
                int o = 2 * oc + ph;
                outp[(size_t)(m0 + rl) * DOUT + o] = s + db_s[o];
            }
            __syncthreads();
        }
    }
}

extern "C" void kernel_launch(void* const* d_in, const int* in_sizes, int n_in,
                              void* d_out, int out_size, void* d_ws, size_t ws_size,
                              hipStream_t stream) {
    const float* x        = (const float*)d_in[0];
    const float* enc_w    = (const float*)d_in[1];
    const float* enc_b    = (const float*)d_in[2];
    const float* log_dt   = (const float*)d_in[3];
    const float* A_re_log = (const float*)d_in[4];
    const float* A_im     = (const float*)d_in[5];
    const float* B_re     = (const float*)d_in[6];
    const float* B_im     = (const float*)d_in[7];
    const float* C_re     = (const float*)d_in[8];
    const float* C_im     = (const float*)d_in[9];
    const float* Dp       = (const float*)d_in[10];
    const float* ln_w     = (const float*)d_in[11];
    const float* ln_b     = (const float*)d_in[12];
    const float* out_w    = (const float*)d_in[13];
    const float* out_b    = (const float*)d_in[14];
    const float* dec_w    = (const float*)d_in[15];
    const float* dec_b    = (const float*)d_in[16];
    float* outp = (float*)d_out;

    float* w = (float*)d_ws;
    const size_t PWE = (size_t)NLAYERS * NSTATE * HDIM;   // 32768
    const size_t MH  = (size_t)M_ROWS * HDIM;             // 8388608
    const size_t VME = (size_t)NLAYERS * HDIM * 64 * 64;  // 4M elems/matrix
    float2* PA64 = (float2*)(w + 4 * PWE);                // 256 KB
    float*  Td   = w + 6 * PWE;                           // 270 KB
    bf16*   Hbuf = (bf16*)(Td + (size_t)NLAYERS * HDIM * 66);  // 16.7 MB bf16
    bf16*   Ut   = Hbuf + MH;                             // 16.7 MB
    bf16*   Yt   = Ut + MH;                               // 16.7 MB
    bf16*   Wt   = Yt + MH;                               // 1 MB (G buffer eliminated)
    bf16*   Wet  = Wt + (size_t)NLAYERS * 512 * HDIM;     // 64 KB
    bf16*   Vg   = Wet + (size_t)HDIM * DIN;              // 8 MB (all layers)
    bf16*   Mg   = Vg + VME;                              // 8 MB (all layers)

    {
        int total = VMB_ + TDB_ + PAB_ + WCB_ + HDIM * DIN / 256;
        k_setup<<<total, 256, 0, stream>>>(log_dt, A_re_log, A_im, B_re, B_im, C_re, C_im,
                                           out_w, enc_w, Td, Vg, Mg, PA64, Wt, Wet);
    }

    dim3 ge(M_ROWS / 128, HDIM / 64);
    k_enc2<<<ge, 256, 0, stream>>>(x, Wet, enc_b, Hbuf, Ut);

    dim3 gconv(HDIM, NBC / 128);
    for (int layer = 0; layer < NLAYERS; ++layer) {
        const float2* pal = PA64 + (size_t)layer * NSTATE * HDIM;
        const float*  tdl = Td + (size_t)layer * HDIM * 66;
        const bf16*   vgl = Vg + (size_t)layer * HDIM * 64 * 64;
        const bf16*   mgl = Mg + (size_t)layer * HDIM * 64 * 64;
        k_conv<<<gconv, 256, 0, stream>>>(Ut, vgl, mgl, tdl, pal, Dp + layer * HDIM, Yt);
        k_gluln<<<M_ROWS / 64, 512, 0, stream>>>(Yt, Wt + (size_t)layer * 512 * HDIM,
                                                 out_b + layer * 2 * HDIM, Hbuf,
                                                 ln_w + layer * HDIM, ln_b + layer * HDIM,
                                                 Ut, dec_w, dec_b, outp,
                                                 layer == NLAYERS - 1 ? 1 : 0);
    }
}